// Round 3
// baseline (227.592 us; speedup 1.0000x reference)
//
#include <hip/hip_runtime.h>
#include <hip/hip_cooperative_groups.h>
#include <math.h>

namespace cg = cooperative_groups;

#define N_NODES 768
#define N_EDGES 12288
#define D_INF 6
#define H 256
#define NB 256   // blocks (1 per CU, coop-resident)
#define NT 512   // threads per block

__global__ __launch_bounds__(NT) void k_fused(
    const float* __restrict__ x, const int* __restrict__ ei,
    const float* __restrict__ Wc1, const float* __restrict__ bc1,
    const float* __restrict__ Wc2, const float* __restrict__ bc2,
    const float* __restrict__ We1, const float* __restrict__ be1,
    const float* __restrict__ We2, float* __restrict__ out,
    int* __restrict__ cnt, int* __restrict__ off, int* __restrict__ pos,
    float* __restrict__ dinv, int* __restrict__ csr_src, float* __restrict__ csr_w,
    float* __restrict__ h1, float* __restrict__ aib, float* __restrict__ ajc)
{
    cg::grid_group grid = cg::this_grid();
    __shared__ __align__(16) float smem[4096];   // 16 KB, reused per phase
    const int t = threadIdx.x, b = blockIdx.x;
    const int g = b * NT + t;
    const int tc = t & 255, th = t >> 8;
    const int* src = ei;
    const int* dst = ei + N_EDGES;

    // ---------------- P0: zero degree counters ----------------
    if (g < N_NODES) cnt[g] = 0;
    grid.sync();

    // ---------------- P1: degree count (edge-parallel, L2 atomics) ----------------
    if (g < N_EDGES) atomicAdd(&cnt[dst[g]], 1);
    grid.sync();

    // ---------------- P2: scan -> off/pos + dinv (block 0) ----------------
    if (b == 0) {
        int* s_c = (int*)smem;        // [768]
        int* s_b = s_c + N_NODES;     // [256]
        for (int v = t; v < N_NODES; v += NT) s_c[v] = cnt[v];
        __syncthreads();
        int a0 = 0, a1 = 0, a2 = 0;
        if (t < 256) {
            a0 = s_c[3 * t]; a1 = s_c[3 * t + 1]; a2 = s_c[3 * t + 2];
            s_b[t] = a0 + a1 + a2;
        }
        __syncthreads();
        for (int o = 1; o < 256; o <<= 1) {
            int v = 0;
            if (t < 256 && t >= o) v = s_b[t - o];
            __syncthreads();
            if (t < 256 && t >= o) s_b[t] += v;
            __syncthreads();
        }
        if (t < 256) {
            int excl = s_b[t] - (a0 + a1 + a2);
            off[3 * t] = excl;          pos[3 * t] = excl;
            off[3 * t + 1] = excl + a0; pos[3 * t + 1] = excl + a0;
            off[3 * t + 2] = excl + a0 + a1; pos[3 * t + 2] = excl + a0 + a1;
        }
        for (int v = t; v < N_NODES; v += NT)
            dinv[v] = 1.0f / sqrtf((float)(cnt[v] + 1));   // +1 self-loop
    }
    grid.sync();

    // ---------------- P3: scatter edges into CSR-by-dst ----------------
    if (g < N_EDGES) {
        int d = dst[g], s = src[g];
        int p = atomicAdd(&pos[d], 1);
        csr_src[p] = s;
        csr_w[p] = dinv[s] * dinv[d];
    }
    grid.sync();

    // ---------------- P4: layer1  h1 = elu( (A x) Wc1 + bc1 ) ----------------
    {
        float* s6 = smem;             // [3][6]
        int w = t >> 6, lane = t & 63;
        if (w < 3) {
            int v = b * 3 + w;
            int base = off[v], c = cnt[v];
            float a[D_INF] = {0.f, 0.f, 0.f, 0.f, 0.f, 0.f};
            if (lane == 0) {
                float dv = dinv[v], wt = dv * dv;   // self-loop
                #pragma unroll
                for (int k = 0; k < D_INF; ++k) a[k] = wt * x[v * D_INF + k];
            }
            for (int n = lane; n < c; n += 64) {
                int s = csr_src[base + n];
                float wt = csr_w[base + n];
                #pragma unroll
                for (int k = 0; k < D_INF; ++k) a[k] = fmaf(wt, x[s * D_INF + k], a[k]);
            }
            #pragma unroll
            for (int m = 32; m >= 1; m >>= 1) {
                #pragma unroll
                for (int k = 0; k < D_INF; ++k) a[k] += __shfl_xor(a[k], m, 64);
            }
            if (lane == 0) {
                #pragma unroll
                for (int k = 0; k < D_INF; ++k) s6[w * D_INF + k] = a[k];
            }
        }
        __syncthreads();
        for (int r = th; r < 3; r += 2) {
            int v = b * 3 + r;
            float acc = bc1[tc];
            #pragma unroll
            for (int k = 0; k < D_INF; ++k)
                acc = fmaf(s6[r * D_INF + k], Wc1[k * H + tc], acc);
            h1[v * H + tc] = (acc > 0.f) ? acc : expm1f(acc);
        }
    }
    grid.sync();

    // ---------------- P5: agg -> h2 -> ai/ajc (3 rows per block, th-split) ----------
    {
        float* s_agg = smem;          // [3][256]
        float* s_h2 = smem + 768;     // [3][256]
        int v0 = b * 3;
        // stage 1: aggregate h1 (rows 0,1 by halves; row 2 by half 0)
        #pragma unroll
        for (int pass = 0; pass < 2; ++pass) {
            int r = (pass == 0) ? th : 2;
            if (pass == 0 || th == 0) {
                int v = v0 + r;
                int base = off[v], c = cnt[v];
                float dv = dinv[v];
                float acc = dv * dv * h1[v * H + tc];
                #pragma unroll 4
                for (int n = 0; n < c; ++n) {
                    int s = csr_src[base + n];
                    acc = fmaf(csr_w[base + n], h1[s * H + tc], acc);
                }
                s_agg[r * H + tc] = acc;
            }
        }
        __syncthreads();
        // stage 2: h2 = agg @ Wc2 + bc2 (half0: rows 0&2, half1: row 1)
        int r0 = (th == 0) ? 0 : 1;
        float h2a = bc2[tc], h2b = h2a;
        #pragma unroll 8
        for (int k = 0; k < H; ++k) {
            float w = Wc2[k * H + tc];
            h2a = fmaf(s_agg[r0 * H + k], w, h2a);
            h2b = fmaf(s_agg[2 * H + k], w, h2b);
        }
        s_h2[r0 * H + tc] = h2a;
        if (th == 0) s_h2[2 * H + tc] = h2b;
        __syncthreads();
        // stage 3: half0 -> ai = h2 @ We1[:H]; half1 -> ajc = h2 @ We1[H:] + be1
        const float* wp = We1 + (size_t)(th * H) * H + tc;
        float a0 = 0.f, a1 = 0.f, a2 = 0.f;
        #pragma unroll 8
        for (int m = 0; m < H; ++m) {
            float w = wp[(size_t)m * H];
            a0 = fmaf(s_h2[m], w, a0);
            a1 = fmaf(s_h2[H + m], w, a1);
            a2 = fmaf(s_h2[2 * H + m], w, a2);
        }
        float* o = (th == 0) ? aib : ajc;
        float bb = (th == 0) ? 0.f : be1[tc];
        o[(v0 + 0) * H + tc] = a0 + bb;
        o[(v0 + 1) * H + tc] = a1 + bb;
        o[(v0 + 2) * H + tc] = a2 + bb;
    }
    grid.sync();

    // ---------------- P6: pair + fused row softmax ----------------
    // logits[i,j] = sum_h relu(ai[i,h] + ajc[j,h]) * w2[h]; be2/temp softmax-invariant
    {
        float* s_ai = smem;           // [3][256]
        float* s_w2 = smem + 768;     // [256]
        float* s_acc = smem + 1024;   // [9][256] partial accs from half 1
        float* red = smem + 3328;     // [3][256]
        int i0 = b * 3;
        if (th == 0) {
            s_w2[tc] = We2[tc];
            #pragma unroll
            for (int i = 0; i < 3; ++i) s_ai[i * H + tc] = aib[(i0 + i) * H + tc];
        }
        __syncthreads();

        float acc[3][3];
        #pragma unroll
        for (int i = 0; i < 3; ++i)
            #pragma unroll
            for (int jj = 0; jj < 3; ++jj) acc[i][jj] = 0.f;

        const float4* A0 = (const float4*)(ajc + (size_t)tc * H);
        const float4* A1 = (const float4*)(ajc + (size_t)(tc + 256) * H);
        const float4* A2 = (const float4*)(ajc + (size_t)(tc + 512) * H);
        const float4* W4 = (const float4*)s_w2;
        const float4* V0 = (const float4*)s_ai;
        const float4* V1 = (const float4*)(s_ai + 256);
        const float4* V2 = (const float4*)(s_ai + 512);

        const int hbase = th * 32;    // each half does 128 h (32 float4)
        #pragma unroll 4
        for (int h4 = hbase; h4 < hbase + 32; ++h4) {
            float4 w = W4[h4];
            float4 av0 = V0[h4], av1 = V1[h4], av2 = V2[h4];
            float4 b0 = A0[h4], b1 = A1[h4], b2 = A2[h4];
            #define STEP(AV, I)                                                \
                acc[I][0] = fmaf(fmaxf(AV.x + b0.x, 0.f), w.x, acc[I][0]);     \
                acc[I][0] = fmaf(fmaxf(AV.y + b0.y, 0.f), w.y, acc[I][0]);     \
                acc[I][0] = fmaf(fmaxf(AV.z + b0.z, 0.f), w.z, acc[I][0]);     \
                acc[I][0] = fmaf(fmaxf(AV.w + b0.w, 0.f), w.w, acc[I][0]);     \
                acc[I][1] = fmaf(fmaxf(AV.x + b1.x, 0.f), w.x, acc[I][1]);     \
                acc[I][1] = fmaf(fmaxf(AV.y + b1.y, 0.f), w.y, acc[I][1]);     \
                acc[I][1] = fmaf(fmaxf(AV.z + b1.z, 0.f), w.z, acc[I][1]);     \
                acc[I][1] = fmaf(fmaxf(AV.w + b1.w, 0.f), w.w, acc[I][1]);     \
                acc[I][2] = fmaf(fmaxf(AV.x + b2.x, 0.f), w.x, acc[I][2]);     \
                acc[I][2] = fmaf(fmaxf(AV.y + b2.y, 0.f), w.y, acc[I][2]);     \
                acc[I][2] = fmaf(fmaxf(AV.z + b2.z, 0.f), w.z, acc[I][2]);     \
                acc[I][2] = fmaf(fmaxf(AV.w + b2.w, 0.f), w.w, acc[I][2]);
            STEP(av0, 0)
            STEP(av1, 1)
            STEP(av2, 2)
            #undef STEP
        }

        if (th == 1) {
            #pragma unroll
            for (int i = 0; i < 3; ++i)
                #pragma unroll
                for (int jj = 0; jj < 3; ++jj)
                    s_acc[(i * 3 + jj) * 256 + tc] = acc[i][jj];
        }
        __syncthreads();
        if (th == 0) {
            #pragma unroll
            for (int i = 0; i < 3; ++i)
                #pragma unroll
                for (int jj = 0; jj < 3; ++jj)
                    acc[i][jj] += s_acc[(i * 3 + jj) * 256 + tc];
            // diagonal mask
            #pragma unroll
            for (int i = 0; i < 3; ++i)
                #pragma unroll
                for (int jj = 0; jj < 3; ++jj)
                    if (tc + jj * 256 == i0 + i) acc[i][jj] = -INFINITY;
            #pragma unroll
            for (int i = 0; i < 3; ++i)
                red[i * 256 + tc] = fmaxf(fmaxf(acc[i][0], acc[i][1]), acc[i][2]);
        }
        __syncthreads();
        for (int s = 128; s > 0; s >>= 1) {
            if (t < s) {
                red[t] = fmaxf(red[t], red[t + s]);
                red[256 + t] = fmaxf(red[256 + t], red[256 + t + s]);
                red[512 + t] = fmaxf(red[512 + t], red[512 + t + s]);
            }
            __syncthreads();
        }
        float mx0 = red[0], mx1 = red[256], mx2 = red[512];
        __syncthreads();   // everyone has read mx before red is reused for sums

        float e[3][3];
        if (th == 0) {
            float s0 = 0.f, s1 = 0.f, s2 = 0.f;
            #pragma unroll
            for (int jj = 0; jj < 3; ++jj) {
                e[0][jj] = __expf(acc[0][jj] - mx0); s0 += e[0][jj];
                e[1][jj] = __expf(acc[1][jj] - mx1); s1 += e[1][jj];
                e[2][jj] = __expf(acc[2][jj] - mx2); s2 += e[2][jj];
            }
            red[tc] = s0; red[256 + tc] = s1; red[512 + tc] = s2;
        }
        __syncthreads();
        for (int s = 128; s > 0; s >>= 1) {
            if (t < s) {
                red[t] += red[t + s];
                red[256 + t] += red[256 + t + s];
                red[512 + t] += red[512 + t + s];
            }
            __syncthreads();
        }
        if (th == 0) {
            float i0v = 1.0f / red[0], i1v = 1.0f / red[256], i2v = 1.0f / red[512];
            #pragma unroll
            for (int jj = 0; jj < 3; ++jj) {
                out[(size_t)(i0 + 0) * N_NODES + tc + jj * 256] = e[0][jj] * i0v;
                out[(size_t)(i0 + 1) * N_NODES + tc + jj * 256] = e[1][jj] * i1v;
                out[(size_t)(i0 + 2) * N_NODES + tc + jj * 256] = e[2][jj] * i2v;
            }
        }
    }
}

extern "C" void kernel_launch(void* const* d_in, const int* in_sizes, int n_in,
                              void* d_out, int out_size, void* d_ws, size_t ws_size,
                              hipStream_t stream) {
    const float* x   = (const float*)d_in[0];
    const int*   ei  = (const int*)d_in[1];
    const float* Wc1 = (const float*)d_in[2];
    const float* bc1 = (const float*)d_in[3];
    const float* Wc2 = (const float*)d_in[4];
    const float* bc2 = (const float*)d_in[5];
    const float* We1 = (const float*)d_in[6];
    const float* be1 = (const float*)d_in[7];
    const float* We2 = (const float*)d_in[8];
    // be2 (d_in[9]) intentionally unused: softmax is shift-invariant.
    float* out = (float*)d_out;

    char* ws = (char*)d_ws;
    int*   cnt     = (int*)(ws + 0);
    int*   off     = (int*)(ws + 3072);
    int*   pos     = (int*)(ws + 6144);
    float* dinv    = (float*)(ws + 9216);
    int*   csr_src = (int*)(ws + 12288);
    float* csr_w   = (float*)(ws + 61440);
    float* h1      = (float*)(ws + 110592);
    float* aib     = (float*)(ws + 897024);
    float* ajc     = (float*)(ws + 1683456);

    void* args[] = {&x, &ei, &Wc1, &bc1, &Wc2, &bc2, &We1, &be1, &We2, &out,
                    &cnt, &off, &pos, &dinv, &csr_src, &csr_w, &h1, &aib, &ajc};
    hipLaunchCooperativeKernel((const void*)k_fused, dim3(NB), dim3(NT), args, 0, stream);
}

// Round 4
// 73.367 us; speedup vs baseline: 3.1021x; 3.1021x over previous
//
#include <hip/hip_runtime.h>
#include <math.h>

#define N_NODES 768
#define N_EDGES 12288
#define D_INF 6
#define H 256
#define LC 768          // per-block match-list capacity (expected ~48)

// ============ k_layer1: per-block degree histogram + edge compaction +
//              h1 = elu( (A x) Wc1 + bc1 ) for 3 nodes per block ============
__global__ __launch_bounds__(512) void k_layer1(
    const float* __restrict__ x, const int* __restrict__ ei,
    const float* __restrict__ Wc1, const float* __restrict__ bc1,
    float* __restrict__ h1, int* __restrict__ list_g, int* __restrict__ nm_g,
    float* __restrict__ dinv_g) {
    __shared__ int s_cnt[N_NODES];
    __shared__ int s_list[LC];
    __shared__ int s_nm;
    __shared__ float s_agg[3][D_INF];
    const int t = threadIdx.x, b = blockIdx.x;
    const int v0 = b * 3;
    const int* src = ei;
    const int* dst = ei + N_EDGES;

    for (int v = t; v < N_NODES; v += 512) s_cnt[v] = 0;
    if (t == 0) s_nm = 0;
    if (t < 3 * D_INF) ((float*)s_agg)[t] = 0.f;
    __syncthreads();

    // histogram all dsts + compact edges hitting this block's 3 nodes
    for (int e = t; e < N_EDGES; e += 512) {
        int d = dst[e];
        atomicAdd(&s_cnt[d], 1);
        unsigned li = (unsigned)(d - v0);
        if (li < 3u) {
            int p = atomicAdd(&s_nm, 1);
            s_list[p] = (e << 2) | (int)li;
        }
    }
    __syncthreads();

    const int nm = s_nm;
    // persist for k_out
    for (int m = t; m < nm; m += 512) list_g[b * LC + m] = s_list[m];
    if (t == 0) nm_g[b] = nm;
    if (b == 0)
        for (int v = t; v < N_NODES; v += 512)
            dinv_g[v] = rsqrtf((float)(s_cnt[v] + 1));

    // aggregate x (one thread per match, 6 LDS float atomics each)
    for (int m = t; m < nm; m += 512) {
        int pk = s_list[m];
        int e = pk >> 2, li = pk & 3;
        int s = src[e];
        float w = rsqrtf((float)(s_cnt[s] + 1)) * rsqrtf((float)(s_cnt[v0 + li] + 1));
        #pragma unroll
        for (int k = 0; k < D_INF; ++k)
            atomicAdd(&s_agg[li][k], w * x[s * D_INF + k]);
    }
    if (t < 3) {   // self-loops
        int v = v0 + t;
        float dv2 = 1.0f / (float)(s_cnt[v] + 1);
        #pragma unroll
        for (int k = 0; k < D_INF; ++k)
            atomicAdd(&s_agg[t][k], dv2 * x[v * D_INF + k]);
    }
    __syncthreads();

    // h1 rows
    const int tc = t & 255, th = t >> 8;
    for (int r = th; r < 3; r += 2) {
        float acc = bc1[tc];
        #pragma unroll
        for (int k = 0; k < D_INF; ++k)
            acc = fmaf(s_agg[r][k], Wc1[k * H + tc], acc);
        h1[(v0 + r) * H + tc] = (acc > 0.f) ? acc : expm1f(acc);
    }
}

// ============ k_out: agg(h1) -> h2 -> ai / ajc for 3 nodes per block ============
__global__ __launch_bounds__(512) void k_out(
    const float* __restrict__ h1, const float* __restrict__ Wc2,
    const float* __restrict__ bc2, const float* __restrict__ We1,
    const float* __restrict__ be1, const int* __restrict__ ei,
    const int* __restrict__ list_g, const int* __restrict__ nm_g,
    const float* __restrict__ dinv, float* __restrict__ aib,
    float* __restrict__ ajc) {
    __shared__ float s_agg[3][H];
    __shared__ float s_h2[3][H];
    const int t = threadIdx.x, b = blockIdx.x;
    const int tc = t & 255, th = t >> 8;
    const int v0 = b * 3;
    const int* src = ei;

    // init with self-loop contribution
    for (int idx = t; idx < 3 * H; idx += 512) {
        int r = idx >> 8, col = idx & 255;
        float dv = dinv[v0 + r];
        ((float*)s_agg)[idx] = dv * dv * h1[(v0 + r) * H + col];
    }
    __syncthreads();

    // neighbor gather (match-strided across thread-halves, LDS float atomics)
    const int nm = nm_g[b];
    for (int m = th; m < nm; m += 2) {
        int pk = list_g[b * LC + m];
        int e = pk >> 2, li = pk & 3;
        int s = src[e];
        float w = dinv[s] * dinv[v0 + li];
        atomicAdd(&s_agg[li][tc], w * h1[s * H + tc]);
    }
    __syncthreads();

    // h2 = agg @ Wc2 + bc2 (half0: rows 0&2, half1: row 1)
    int r0 = (th == 0) ? 0 : 1;
    float h2a = bc2[tc], h2b = h2a;
    #pragma unroll 8
    for (int k = 0; k < H; ++k) {
        float w = Wc2[k * H + tc];
        h2a = fmaf(s_agg[r0][k], w, h2a);
        h2b = fmaf(s_agg[2][k], w, h2b);
    }
    s_h2[r0][tc] = h2a;
    if (th == 0) s_h2[2][tc] = h2b;
    __syncthreads();

    // half0 -> ai = h2 @ We1[:H]; half1 -> ajc = h2 @ We1[H:] + be1
    const float* wp = We1 + (size_t)(th * H) * H + tc;
    float a0 = 0.f, a1 = 0.f, a2 = 0.f;
    #pragma unroll 8
    for (int m = 0; m < H; ++m) {
        float w = wp[(size_t)m * H];
        a0 = fmaf(s_h2[0][m], w, a0);
        a1 = fmaf(s_h2[1][m], w, a1);
        a2 = fmaf(s_h2[2][m], w, a2);
    }
    float* o = (th == 0) ? aib : ajc;
    float bb = (th == 0) ? 0.f : be1[tc];
    o[(v0 + 0) * H + tc] = a0 + bb;
    o[(v0 + 1) * H + tc] = a1 + bb;
    o[(v0 + 2) * H + tc] = a2 + bb;
}

// ============ k_pair: logits + fused row softmax (512 thr, h-split) ============
// logits[i,j] = sum_h relu(ai[i,h] + ajc[j,h]) * w2[h]; be2/temp softmax-invariant
__global__ __launch_bounds__(512) void k_pair(
    const float* __restrict__ aib, const float* __restrict__ ajc,
    const float* __restrict__ We2, float* __restrict__ out) {
    __shared__ __align__(16) float smem[4096];
    float* s_ai = smem;           // [3][256]
    float* s_w2 = smem + 768;     // [256]
    float* s_acc = smem + 1024;   // [9][256]
    float* red = smem + 3328;     // [3][256]
    const int t = threadIdx.x, b = blockIdx.x;
    const int tc = t & 255, th = t >> 8;
    const int i0 = b * 3;

    if (th == 0) {
        s_w2[tc] = We2[tc];
        #pragma unroll
        for (int i = 0; i < 3; ++i) s_ai[i * H + tc] = aib[(i0 + i) * H + tc];
    }
    __syncthreads();

    float acc[3][3];
    #pragma unroll
    for (int i = 0; i < 3; ++i)
        #pragma unroll
        for (int jj = 0; jj < 3; ++jj) acc[i][jj] = 0.f;

    const float4* A0 = (const float4*)(ajc + (size_t)tc * H);
    const float4* A1 = (const float4*)(ajc + (size_t)(tc + 256) * H);
    const float4* A2 = (const float4*)(ajc + (size_t)(tc + 512) * H);
    const float4* W4 = (const float4*)s_w2;
    const float4* V0 = (const float4*)s_ai;
    const float4* V1 = (const float4*)(s_ai + 256);
    const float4* V2 = (const float4*)(s_ai + 512);

    const int hbase = th * 32;    // each half covers 128 h (32 float4)
    #pragma unroll 4
    for (int h4 = hbase; h4 < hbase + 32; ++h4) {
        float4 w = W4[h4];
        float4 av0 = V0[h4], av1 = V1[h4], av2 = V2[h4];
        float4 b0 = A0[h4], b1 = A1[h4], b2 = A2[h4];
        #define STEP(AV, I)                                                \
            acc[I][0] = fmaf(fmaxf(AV.x + b0.x, 0.f), w.x, acc[I][0]);     \
            acc[I][0] = fmaf(fmaxf(AV.y + b0.y, 0.f), w.y, acc[I][0]);     \
            acc[I][0] = fmaf(fmaxf(AV.z + b0.z, 0.f), w.z, acc[I][0]);     \
            acc[I][0] = fmaf(fmaxf(AV.w + b0.w, 0.f), w.w, acc[I][0]);     \
            acc[I][1] = fmaf(fmaxf(AV.x + b1.x, 0.f), w.x, acc[I][1]);     \
            acc[I][1] = fmaf(fmaxf(AV.y + b1.y, 0.f), w.y, acc[I][1]);     \
            acc[I][1] = fmaf(fmaxf(AV.z + b1.z, 0.f), w.z, acc[I][1]);     \
            acc[I][1] = fmaf(fmaxf(AV.w + b1.w, 0.f), w.w, acc[I][1]);     \
            acc[I][2] = fmaf(fmaxf(AV.x + b2.x, 0.f), w.x, acc[I][2]);     \
            acc[I][2] = fmaf(fmaxf(AV.y + b2.y, 0.f), w.y, acc[I][2]);     \
            acc[I][2] = fmaf(fmaxf(AV.z + b2.z, 0.f), w.z, acc[I][2]);     \
            acc[I][2] = fmaf(fmaxf(AV.w + b2.w, 0.f), w.w, acc[I][2]);
        STEP(av0, 0)
        STEP(av1, 1)
        STEP(av2, 2)
        #undef STEP
    }

    if (th == 1) {
        #pragma unroll
        for (int i = 0; i < 3; ++i)
            #pragma unroll
            for (int jj = 0; jj < 3; ++jj)
                s_acc[(i * 3 + jj) * 256 + tc] = acc[i][jj];
    }
    __syncthreads();
    if (th == 0) {
        #pragma unroll
        for (int i = 0; i < 3; ++i)
            #pragma unroll
            for (int jj = 0; jj < 3; ++jj)
                acc[i][jj] += s_acc[(i * 3 + jj) * 256 + tc];
        #pragma unroll
        for (int i = 0; i < 3; ++i)
            #pragma unroll
            for (int jj = 0; jj < 3; ++jj)
                if (tc + jj * 256 == i0 + i) acc[i][jj] = -INFINITY;
        #pragma unroll
        for (int i = 0; i < 3; ++i)
            red[i * 256 + tc] = fmaxf(fmaxf(acc[i][0], acc[i][1]), acc[i][2]);
    }
    __syncthreads();
    for (int s = 128; s > 0; s >>= 1) {
        if (t < s) {
            red[t] = fmaxf(red[t], red[t + s]);
            red[256 + t] = fmaxf(red[256 + t], red[256 + t + s]);
            red[512 + t] = fmaxf(red[512 + t], red[512 + t + s]);
        }
        __syncthreads();
    }
    float mx0 = red[0], mx1 = red[256], mx2 = red[512];
    __syncthreads();

    float e[3][3];
    if (th == 0) {
        float s0 = 0.f, s1 = 0.f, s2 = 0.f;
        #pragma unroll
        for (int jj = 0; jj < 3; ++jj) {
            e[0][jj] = __expf(acc[0][jj] - mx0); s0 += e[0][jj];
            e[1][jj] = __expf(acc[1][jj] - mx1); s1 += e[1][jj];
            e[2][jj] = __expf(acc[2][jj] - mx2); s2 += e[2][jj];
        }
        red[tc] = s0; red[256 + tc] = s1; red[512 + tc] = s2;
    }
    __syncthreads();
    for (int s = 128; s > 0; s >>= 1) {
        if (t < s) {
            red[t] += red[t + s];
            red[256 + t] += red[256 + t + s];
            red[512 + t] += red[512 + t + s];
        }
        __syncthreads();
    }
    if (th == 0) {
        float r0 = 1.0f / red[0], r1 = 1.0f / red[256], r2 = 1.0f / red[512];
        #pragma unroll
        for (int jj = 0; jj < 3; ++jj) {
            out[(size_t)(i0 + 0) * N_NODES + tc + jj * 256] = e[0][jj] * r0;
            out[(size_t)(i0 + 1) * N_NODES + tc + jj * 256] = e[1][jj] * r1;
            out[(size_t)(i0 + 2) * N_NODES + tc + jj * 256] = e[2][jj] * r2;
        }
    }
}

extern "C" void kernel_launch(void* const* d_in, const int* in_sizes, int n_in,
                              void* d_out, int out_size, void* d_ws, size_t ws_size,
                              hipStream_t stream) {
    const float* x   = (const float*)d_in[0];
    const int*   ei  = (const int*)d_in[1];
    const float* Wc1 = (const float*)d_in[2];
    const float* bc1 = (const float*)d_in[3];
    const float* Wc2 = (const float*)d_in[4];
    const float* bc2 = (const float*)d_in[5];
    const float* We1 = (const float*)d_in[6];
    const float* be1 = (const float*)d_in[7];
    const float* We2 = (const float*)d_in[8];
    // be2 (d_in[9]) intentionally unused: softmax is shift-invariant.
    float* out = (float*)d_out;

    char* ws = (char*)d_ws;
    float* h1     = (float*)(ws + 0);          // 768*256*4 = 786432
    float* aib    = (float*)(ws + 786432);     // 786432
    float* ajc    = (float*)(ws + 1572864);    // 786432
    float* dinv   = (float*)(ws + 2359296);    // 3072
    int*   nm_g   = (int*)(ws + 2362368);      // 1024
    int*   list_g = (int*)(ws + 2363392);      // 256*LC*4 = 786432

    k_layer1<<<N_NODES / 3, 512, 0, stream>>>(x, ei, Wc1, bc1, h1, list_g, nm_g, dinv);
    k_out<<<N_NODES / 3, 512, 0, stream>>>(h1, Wc2, bc2, We1, be1, ei,
                                           list_g, nm_g, dinv, aib, ajc);
    k_pair<<<N_NODES / 3, 512, 0, stream>>>(aib, ajc, We2, out);
}

// Round 5
// 70.143 us; speedup vs baseline: 3.2447x; 1.0460x over previous
//
#include <hip/hip_runtime.h>
#include <math.h>

#define N_NODES 768
#define N_EDGES 12288
#define D_INF 6
#define H 256
#define CAP 128          // bucket capacity per node (mean deg 16, binomial tail ~0)
#define PS 1540          // s_part row stride (floats): 6*256 rounded up, %32==4

// ============ k_scatter: bucket edges by dst with global atomics ============
__global__ void k_scatter(const int* __restrict__ src, const int* __restrict__ dst,
                          int* __restrict__ cnt, int* __restrict__ slots) {
    int e = blockIdx.x * blockDim.x + threadIdx.x;
    if (e >= N_EDGES) return;
    int d = dst[e];
    int p = atomicAdd(&cnt[d], 1);
    if (p < CAP) slots[d * CAP + p] = src[e];
}

// ============ k_layer1: h1 = elu( (A x) Wc1 + bc1 ), 1 node per block ============
__global__ __launch_bounds__(256) void k_layer1(
    const float* __restrict__ x, const float* __restrict__ Wc1,
    const float* __restrict__ bc1, const int* __restrict__ cnt,
    const int* __restrict__ slots, float* __restrict__ h1) {
    __shared__ float s6[8];
    const int v = blockIdx.x, t = threadIdx.x;
    const int c = cnt[v];
    const float dv = rsqrtf((float)(c + 1));
    if (t < 64) {
        float a[D_INF] = {0.f, 0.f, 0.f, 0.f, 0.f, 0.f};
        if (t == 0) {
            float w = dv * dv;   // self-loop
            #pragma unroll
            for (int k = 0; k < D_INF; ++k) a[k] = w * x[v * D_INF + k];
        }
        for (int n = t; n < c; n += 64) {
            int s = slots[v * CAP + n];
            float w = rsqrtf((float)(cnt[s] + 1)) * dv;
            #pragma unroll
            for (int k = 0; k < D_INF; ++k) a[k] = fmaf(w, x[s * D_INF + k], a[k]);
        }
        #pragma unroll
        for (int m = 32; m >= 1; m >>= 1) {
            #pragma unroll
            for (int k = 0; k < D_INF; ++k) a[k] += __shfl_xor(a[k], m, 64);
        }
        if (t == 0) {
            #pragma unroll
            for (int k = 0; k < D_INF; ++k) s6[k] = a[k];
        }
    }
    __syncthreads();
    float acc = bc1[t];
    #pragma unroll
    for (int k = 0; k < D_INF; ++k) acc = fmaf(s6[k], Wc1[k * H + t], acc);
    h1[v * H + t] = (acc > 0.f) ? acc : expm1f(acc);
}

// ============ k_out: agg(h1) -> h2 -> ai/ajc, 3 rows/block, k-split 16 waves ============
__global__ __launch_bounds__(1024) void k_out(
    const float* __restrict__ h1, const float* __restrict__ Wc2,
    const float* __restrict__ bc2, const float* __restrict__ We1,
    const float* __restrict__ be1, const int* __restrict__ cnt,
    const int* __restrict__ slots, float* __restrict__ aib,
    float* __restrict__ ajc) {
    __shared__ float s_agg[3][H];
    __shared__ float s_h2[3][H];
    __shared__ __align__(16) float s_part[16 * PS];   // 98.6 KB
    const int t = threadIdx.x, b = blockIdx.x;
    const int tc = t & 255, th = t >> 8;
    const int w = t >> 6, lane = t & 63;
    const int v0 = b * 3;

    // init with self-loop contribution
    if (t < 3 * H) {
        int r = t >> 8;
        float dv = rsqrtf((float)(cnt[v0 + r] + 1));
        s_agg[r][tc] = dv * dv * h1[(v0 + r) * H + tc];
    }
    __syncthreads();

    // neighbor gather: quarter th takes every 4th neighbor, LDS-atomic combine
    #pragma unroll
    for (int r = 0; r < 3; ++r) {
        int cr = cnt[v0 + r];
        float dvr = rsqrtf((float)(cr + 1));
        float p = 0.f;
        for (int n = th; n < cr; n += 4) {
            int s = slots[(v0 + r) * CAP + n];
            float wt = rsqrtf((float)(cnt[s] + 1)) * dvr;
            p = fmaf(wt, h1[s * H + tc], p);
        }
        atomicAdd(&s_agg[r][tc], p);
    }
    __syncthreads();

    // ---- phase A: h2 = agg @ Wc2 + bc2, k-split across 16 waves ----
    const int k0 = w * 16;
    {
        float4 a0 = {0.f, 0.f, 0.f, 0.f}, a1 = a0, a2 = a0;
        #pragma unroll
        for (int kk = 0; kk < 16; ++kk) {
            int k = k0 + kk;
            float4 wr = *(const float4*)(Wc2 + (size_t)k * H + lane * 4);
            float g0 = s_agg[0][k], g1 = s_agg[1][k], g2 = s_agg[2][k];
            a0.x = fmaf(g0, wr.x, a0.x); a0.y = fmaf(g0, wr.y, a0.y);
            a0.z = fmaf(g0, wr.z, a0.z); a0.w = fmaf(g0, wr.w, a0.w);
            a1.x = fmaf(g1, wr.x, a1.x); a1.y = fmaf(g1, wr.y, a1.y);
            a1.z = fmaf(g1, wr.z, a1.z); a1.w = fmaf(g1, wr.w, a1.w);
            a2.x = fmaf(g2, wr.x, a2.x); a2.y = fmaf(g2, wr.y, a2.y);
            a2.z = fmaf(g2, wr.z, a2.z); a2.w = fmaf(g2, wr.w, a2.w);
        }
        float* pb = s_part + w * PS;
        *(float4*)(pb + 0 * H + lane * 4) = a0;
        *(float4*)(pb + 1 * H + lane * 4) = a1;
        *(float4*)(pb + 2 * H + lane * 4) = a2;
    }
    __syncthreads();
    if (t < 3 * H) {
        int r = t >> 8;
        float v = bc2[tc];
        #pragma unroll
        for (int ww = 0; ww < 16; ++ww) v += s_part[ww * PS + r * H + tc];
        s_h2[r][tc] = v;
    }
    __syncthreads();

    // ---- phase B: ai = h2 @ We1[:H]; aj = h2 @ We1[H:] + be1 ----
    {
        float4 q0 = {0.f, 0.f, 0.f, 0.f}, q1 = q0, q2 = q0, q3 = q0, q4 = q0, q5 = q0;
        #pragma unroll
        for (int mm = 0; mm < 16; ++mm) {
            int m = k0 + mm;
            float4 wa = *(const float4*)(We1 + (size_t)m * H + lane * 4);
            float4 wb = *(const float4*)(We1 + (size_t)(H + m) * H + lane * 4);
            float g0 = s_h2[0][m], g1 = s_h2[1][m], g2 = s_h2[2][m];
            q0.x = fmaf(g0, wa.x, q0.x); q0.y = fmaf(g0, wa.y, q0.y);
            q0.z = fmaf(g0, wa.z, q0.z); q0.w = fmaf(g0, wa.w, q0.w);
            q1.x = fmaf(g1, wa.x, q1.x); q1.y = fmaf(g1, wa.y, q1.y);
            q1.z = fmaf(g1, wa.z, q1.z); q1.w = fmaf(g1, wa.w, q1.w);
            q2.x = fmaf(g2, wa.x, q2.x); q2.y = fmaf(g2, wa.y, q2.y);
            q2.z = fmaf(g2, wa.z, q2.z); q2.w = fmaf(g2, wa.w, q2.w);
            q3.x = fmaf(g0, wb.x, q3.x); q3.y = fmaf(g0, wb.y, q3.y);
            q3.z = fmaf(g0, wb.z, q3.z); q3.w = fmaf(g0, wb.w, q3.w);
            q4.x = fmaf(g1, wb.x, q4.x); q4.y = fmaf(g1, wb.y, q4.y);
            q4.z = fmaf(g1, wb.z, q4.z); q4.w = fmaf(g1, wb.w, q4.w);
            q5.x = fmaf(g2, wb.x, q5.x); q5.y = fmaf(g2, wb.y, q5.y);
            q5.z = fmaf(g2, wb.z, q5.z); q5.w = fmaf(g2, wb.w, q5.w);
        }
        float* pb = s_part + w * PS;
        *(float4*)(pb + 0 * H + lane * 4) = q0;
        *(float4*)(pb + 1 * H + lane * 4) = q1;
        *(float4*)(pb + 2 * H + lane * 4) = q2;
        *(float4*)(pb + 3 * H + lane * 4) = q3;
        *(float4*)(pb + 4 * H + lane * 4) = q4;
        *(float4*)(pb + 5 * H + lane * 4) = q5;
    }
    __syncthreads();
    for (int o = t; o < 6 * H; o += 1024) {
        int r6 = o >> 8, c = o & 255;
        float v = 0.f;
        #pragma unroll
        for (int ww = 0; ww < 16; ++ww) v += s_part[ww * PS + r6 * H + c];
        if (r6 < 3) aib[(v0 + r6) * H + c] = v;
        else        ajc[(v0 + r6 - 3) * H + c] = v + be1[c];
    }
}

// ============ k_pair: logits + fused row softmax (1024 thr, 4-way h-split) ============
// logits[i,j] = sum_h relu(ai[i,h] + ajc[j,h]) * w2[h]; be2/temp softmax-invariant
__global__ __launch_bounds__(1024) void k_pair(
    const float* __restrict__ aib, const float* __restrict__ ajc,
    const float* __restrict__ We2, float* __restrict__ out) {
    __shared__ __align__(16) float s_ai[3 * H];
    __shared__ __align__(16) float s_w2[H];
    __shared__ float s_acc[3 * 9 * 256];   // quarters 1..3 partials, 27.6 KB
    __shared__ float red[3 * 256];
    const int t = threadIdx.x, b = blockIdx.x;
    const int tc = t & 255, th = t >> 8;
    const int i0 = b * 3;

    if (th == 0) s_w2[tc] = We2[tc];
    else s_ai[(th - 1) * H + tc] = aib[(i0 + th - 1) * H + tc];
    __syncthreads();

    float acc[3][3];
    #pragma unroll
    for (int i = 0; i < 3; ++i)
        #pragma unroll
        for (int jj = 0; jj < 3; ++jj) acc[i][jj] = 0.f;

    const float4* A0 = (const float4*)(ajc + (size_t)tc * H);
    const float4* A1 = (const float4*)(ajc + (size_t)(tc + 256) * H);
    const float4* A2 = (const float4*)(ajc + (size_t)(tc + 512) * H);
    const float4* W4 = (const float4*)s_w2;
    const float4* V0 = (const float4*)s_ai;
    const float4* V1 = (const float4*)(s_ai + 256);
    const float4* V2 = (const float4*)(s_ai + 512);

    const int hbase = th * 16;   // each quarter covers 64 h (16 float4)
    #pragma unroll 4
    for (int q = 0; q < 16; ++q) {
        int h4 = hbase + q;
        float4 w = W4[h4];
        float4 av0 = V0[h4], av1 = V1[h4], av2 = V2[h4];
        float4 b0 = A0[h4], b1 = A1[h4], b2 = A2[h4];
        #define STEP(AV, I)                                                \
            acc[I][0] = fmaf(fmaxf(AV.x + b0.x, 0.f), w.x, acc[I][0]);     \
            acc[I][0] = fmaf(fmaxf(AV.y + b0.y, 0.f), w.y, acc[I][0]);     \
            acc[I][0] = fmaf(fmaxf(AV.z + b0.z, 0.f), w.z, acc[I][0]);     \
            acc[I][0] = fmaf(fmaxf(AV.w + b0.w, 0.f), w.w, acc[I][0]);     \
            acc[I][1] = fmaf(fmaxf(AV.x + b1.x, 0.f), w.x, acc[I][1]);     \
            acc[I][1] = fmaf(fmaxf(AV.y + b1.y, 0.f), w.y, acc[I][1]);     \
            acc[I][1] = fmaf(fmaxf(AV.z + b1.z, 0.f), w.z, acc[I][1]);     \
            acc[I][1] = fmaf(fmaxf(AV.w + b1.w, 0.f), w.w, acc[I][1]);     \
            acc[I][2] = fmaf(fmaxf(AV.x + b2.x, 0.f), w.x, acc[I][2]);     \
            acc[I][2] = fmaf(fmaxf(AV.y + b2.y, 0.f), w.y, acc[I][2]);     \
            acc[I][2] = fmaf(fmaxf(AV.z + b2.z, 0.f), w.z, acc[I][2]);     \
            acc[I][2] = fmaf(fmaxf(AV.w + b2.w, 0.f), w.w, acc[I][2]);
        STEP(av0, 0)
        STEP(av1, 1)
        STEP(av2, 2)
        #undef STEP
    }

    if (th > 0) {
        #pragma unroll
        for (int i = 0; i < 3; ++i)
            #pragma unroll
            for (int jj = 0; jj < 3; ++jj)
                s_acc[((th - 1) * 9 + i * 3 + jj) * 256 + tc] = acc[i][jj];
    }
    __syncthreads();
    if (th == 0) {
        #pragma unroll
        for (int qq = 0; qq < 3; ++qq)
            #pragma unroll
            for (int i = 0; i < 3; ++i)
                #pragma unroll
                for (int jj = 0; jj < 3; ++jj)
                    acc[i][jj] += s_acc[(qq * 9 + i * 3 + jj) * 256 + tc];
        #pragma unroll
        for (int i = 0; i < 3; ++i)
            #pragma unroll
            for (int jj = 0; jj < 3; ++jj)
                if (tc + jj * 256 == i0 + i) acc[i][jj] = -INFINITY;
        #pragma unroll
        for (int i = 0; i < 3; ++i)
            red[i * 256 + tc] = fmaxf(fmaxf(acc[i][0], acc[i][1]), acc[i][2]);
    }
    __syncthreads();
    for (int s = 128; s > 0; s >>= 1) {
        if (t < s) {
            red[t] = fmaxf(red[t], red[t + s]);
            red[256 + t] = fmaxf(red[256 + t], red[256 + t + s]);
            red[512 + t] = fmaxf(red[512 + t], red[512 + t + s]);
        }
        __syncthreads();
    }
    float mx0 = red[0], mx1 = red[256], mx2 = red[512];
    __syncthreads();

    float e[3][3];
    if (th == 0) {
        float s0 = 0.f, s1 = 0.f, s2 = 0.f;
        #pragma unroll
        for (int jj = 0; jj < 3; ++jj) {
            e[0][jj] = __expf(acc[0][jj] - mx0); s0 += e[0][jj];
            e[1][jj] = __expf(acc[1][jj] - mx1); s1 += e[1][jj];
            e[2][jj] = __expf(acc[2][jj] - mx2); s2 += e[2][jj];
        }
        red[tc] = s0; red[256 + tc] = s1; red[512 + tc] = s2;
    }
    __syncthreads();
    for (int s = 128; s > 0; s >>= 1) {
        if (t < s) {
            red[t] += red[t + s];
            red[256 + t] += red[256 + t + s];
            red[512 + t] += red[512 + t + s];
        }
        __syncthreads();
    }
    if (th == 0) {
        float r0 = 1.0f / red[0], r1 = 1.0f / red[256], r2 = 1.0f / red[512];
        #pragma unroll
        for (int jj = 0; jj < 3; ++jj) {
            out[(size_t)(i0 + 0) * N_NODES + tc + jj * 256] = e[0][jj] * r0;
            out[(size_t)(i0 + 1) * N_NODES + tc + jj * 256] = e[1][jj] * r1;
            out[(size_t)(i0 + 2) * N_NODES + tc + jj * 256] = e[2][jj] * r2;
        }
    }
}

extern "C" void kernel_launch(void* const* d_in, const int* in_sizes, int n_in,
                              void* d_out, int out_size, void* d_ws, size_t ws_size,
                              hipStream_t stream) {
    const float* x   = (const float*)d_in[0];
    const int*   ei  = (const int*)d_in[1];
    const float* Wc1 = (const float*)d_in[2];
    const float* bc1 = (const float*)d_in[3];
    const float* Wc2 = (const float*)d_in[4];
    const float* bc2 = (const float*)d_in[5];
    const float* We1 = (const float*)d_in[6];
    const float* be1 = (const float*)d_in[7];
    const float* We2 = (const float*)d_in[8];
    // be2 (d_in[9]) intentionally unused: softmax is shift-invariant.
    float* out = (float*)d_out;

    char* ws = (char*)d_ws;
    int*   cnt   = (int*)(ws + 0);            // 3072
    int*   slots = (int*)(ws + 4096);         // 768*128*4 = 393216
    float* h1    = (float*)(ws + 397312);     // 786432
    float* aib   = (float*)(ws + 1183744);    // 786432
    float* ajc   = (float*)(ws + 1970176);    // 786432

    const int* srcA = ei;             // edge_index[0]
    const int* dstA = ei + N_EDGES;   // edge_index[1]

    hipMemsetAsync(cnt, 0, N_NODES * sizeof(int), stream);
    k_scatter<<<N_EDGES / 256, 256, 0, stream>>>(srcA, dstA, cnt, slots);
    k_layer1<<<N_NODES, 256, 0, stream>>>(x, Wc1, bc1, cnt, slots, h1);
    k_out<<<N_NODES / 3, 1024, 0, stream>>>(h1, Wc2, bc2, We1, be1, cnt, slots, aib, ajc);
    k_pair<<<N_NODES / 3, 1024, 0, stream>>>(aib, ajc, We2, out);
}

// Round 6
// 70.002 us; speedup vs baseline: 3.2512x; 1.0020x over previous
//
#include <hip/hip_runtime.h>
#include <math.h>

#define N_NODES 768
#define N_EDGES 12288
#define D_INF 6
#define H 256
#define CAP 128          // bucket capacity per node (mean deg 16, binomial tail ~0)
#define PS 1540          // s_part row stride (floats): 6*256 rounded up, %32==4

// ============ k_zero: zero degree counters (replaces hipMemsetAsync:
//              an in-graph fillBufferAligned dispatch costs ~39us!) ============
__global__ __launch_bounds__(768) void k_zero(int* __restrict__ cnt) {
    cnt[threadIdx.x] = 0;
}

// ============ k_scatter: bucket edges by dst with global atomics ============
__global__ void k_scatter(const int* __restrict__ src, const int* __restrict__ dst,
                          int* __restrict__ cnt, int* __restrict__ slots) {
    int e = blockIdx.x * blockDim.x + threadIdx.x;
    if (e >= N_EDGES) return;
    int d = dst[e];
    int p = atomicAdd(&cnt[d], 1);
    if (p < CAP) slots[d * CAP + p] = src[e];
}

// ============ k_layer1: h1 = elu( (A x) Wc1 + bc1 ), 1 node per block ============
__global__ __launch_bounds__(256) void k_layer1(
    const float* __restrict__ x, const float* __restrict__ Wc1,
    const float* __restrict__ bc1, const int* __restrict__ cnt,
    const int* __restrict__ slots, float* __restrict__ h1) {
    __shared__ float s6[8];
    const int v = blockIdx.x, t = threadIdx.x;
    const int c = cnt[v];
    const float dv = rsqrtf((float)(c + 1));
    if (t < 64) {
        float a[D_INF] = {0.f, 0.f, 0.f, 0.f, 0.f, 0.f};
        if (t == 0) {
            float w = dv * dv;   // self-loop
            #pragma unroll
            for (int k = 0; k < D_INF; ++k) a[k] = w * x[v * D_INF + k];
        }
        for (int n = t; n < c; n += 64) {
            int s = slots[v * CAP + n];
            float w = rsqrtf((float)(cnt[s] + 1)) * dv;
            #pragma unroll
            for (int k = 0; k < D_INF; ++k) a[k] = fmaf(w, x[s * D_INF + k], a[k]);
        }
        #pragma unroll
        for (int m = 32; m >= 1; m >>= 1) {
            #pragma unroll
            for (int k = 0; k < D_INF; ++k) a[k] += __shfl_xor(a[k], m, 64);
        }
        if (t == 0) {
            #pragma unroll
            for (int k = 0; k < D_INF; ++k) s6[k] = a[k];
        }
    }
    __syncthreads();
    float acc = bc1[t];
    #pragma unroll
    for (int k = 0; k < D_INF; ++k) acc = fmaf(s6[k], Wc1[k * H + t], acc);
    h1[v * H + t] = (acc > 0.f) ? acc : expm1f(acc);
}

// ============ k_out: agg(h1) -> h2 -> ai/ajc, 3 rows/block, k-split 16 waves ============
__global__ __launch_bounds__(1024) void k_out(
    const float* __restrict__ h1, const float* __restrict__ Wc2,
    const float* __restrict__ bc2, const float* __restrict__ We1,
    const float* __restrict__ be1, const int* __restrict__ cnt,
    const int* __restrict__ slots, float* __restrict__ aib,
    float* __restrict__ ajc) {
    __shared__ float s_agg[3][H];
    __shared__ float s_h2[3][H];
    __shared__ __align__(16) float s_part[16 * PS];   // 98.6 KB
    const int t = threadIdx.x, b = blockIdx.x;
    const int tc = t & 255, th = t >> 8;
    const int w = t >> 6, lane = t & 63;
    const int v0 = b * 3;

    // init with self-loop contribution
    if (t < 3 * H) {
        int r = t >> 8;
        float dv = rsqrtf((float)(cnt[v0 + r] + 1));
        s_agg[r][tc] = dv * dv * h1[(v0 + r) * H + tc];
    }
    __syncthreads();

    // neighbor gather: quarter th takes every 4th neighbor, LDS-atomic combine
    #pragma unroll
    for (int r = 0; r < 3; ++r) {
        int cr = cnt[v0 + r];
        float dvr = rsqrtf((float)(cr + 1));
        float p = 0.f;
        for (int n = th; n < cr; n += 4) {
            int s = slots[(v0 + r) * CAP + n];
            float wt = rsqrtf((float)(cnt[s] + 1)) * dvr;
            p = fmaf(wt, h1[s * H + tc], p);
        }
        atomicAdd(&s_agg[r][tc], p);
    }
    __syncthreads();

    // ---- phase A: h2 = agg @ Wc2 + bc2, k-split across 16 waves ----
    const int k0 = w * 16;
    {
        float4 a0 = {0.f, 0.f, 0.f, 0.f}, a1 = a0, a2 = a0;
        #pragma unroll
        for (int kk = 0; kk < 16; ++kk) {
            int k = k0 + kk;
            float4 wr = *(const float4*)(Wc2 + (size_t)k * H + lane * 4);
            float g0 = s_agg[0][k], g1 = s_agg[1][k], g2 = s_agg[2][k];
            a0.x = fmaf(g0, wr.x, a0.x); a0.y = fmaf(g0, wr.y, a0.y);
            a0.z = fmaf(g0, wr.z, a0.z); a0.w = fmaf(g0, wr.w, a0.w);
            a1.x = fmaf(g1, wr.x, a1.x); a1.y = fmaf(g1, wr.y, a1.y);
            a1.z = fmaf(g1, wr.z, a1.z); a1.w = fmaf(g1, wr.w, a1.w);
            a2.x = fmaf(g2, wr.x, a2.x); a2.y = fmaf(g2, wr.y, a2.y);
            a2.z = fmaf(g2, wr.z, a2.z); a2.w = fmaf(g2, wr.w, a2.w);
        }
        float* pb = s_part + w * PS;
        *(float4*)(pb + 0 * H + lane * 4) = a0;
        *(float4*)(pb + 1 * H + lane * 4) = a1;
        *(float4*)(pb + 2 * H + lane * 4) = a2;
    }
    __syncthreads();
    if (t < 3 * H) {
        int r = t >> 8;
        float v = bc2[tc];
        #pragma unroll
        for (int ww = 0; ww < 16; ++ww) v += s_part[ww * PS + r * H + tc];
        s_h2[r][tc] = v;
    }
    __syncthreads();

    // ---- phase B: ai = h2 @ We1[:H]; aj = h2 @ We1[H:] + be1 ----
    {
        float4 q0 = {0.f, 0.f, 0.f, 0.f}, q1 = q0, q2 = q0, q3 = q0, q4 = q0, q5 = q0;
        #pragma unroll
        for (int mm = 0; mm < 16; ++mm) {
            int m = k0 + mm;
            float4 wa = *(const float4*)(We1 + (size_t)m * H + lane * 4);
            float4 wb = *(const float4*)(We1 + (size_t)(H + m) * H + lane * 4);
            float g0 = s_h2[0][m], g1 = s_h2[1][m], g2 = s_h2[2][m];
            q0.x = fmaf(g0, wa.x, q0.x); q0.y = fmaf(g0, wa.y, q0.y);
            q0.z = fmaf(g0, wa.z, q0.z); q0.w = fmaf(g0, wa.w, q0.w);
            q1.x = fmaf(g1, wa.x, q1.x); q1.y = fmaf(g1, wa.y, q1.y);
            q1.z = fmaf(g1, wa.z, q1.z); q1.w = fmaf(g1, wa.w, q1.w);
            q2.x = fmaf(g2, wa.x, q2.x); q2.y = fmaf(g2, wa.y, q2.y);
            q2.z = fmaf(g2, wa.z, q2.z); q2.w = fmaf(g2, wa.w, q2.w);
            q3.x = fmaf(g0, wb.x, q3.x); q3.y = fmaf(g0, wb.y, q3.y);
            q3.z = fmaf(g0, wb.z, q3.z); q3.w = fmaf(g0, wb.w, q3.w);
            q4.x = fmaf(g1, wb.x, q4.x); q4.y = fmaf(g1, wb.y, q4.y);
            q4.z = fmaf(g1, wb.z, q4.z); q4.w = fmaf(g1, wb.w, q4.w);
            q5.x = fmaf(g2, wb.x, q5.x); q5.y = fmaf(g2, wb.y, q5.y);
            q5.z = fmaf(g2, wb.z, q5.z); q5.w = fmaf(g2, wb.w, q5.w);
        }
        float* pb = s_part + w * PS;
        *(float4*)(pb + 0 * H + lane * 4) = q0;
        *(float4*)(pb + 1 * H + lane * 4) = q1;
        *(float4*)(pb + 2 * H + lane * 4) = q2;
        *(float4*)(pb + 3 * H + lane * 4) = q3;
        *(float4*)(pb + 4 * H + lane * 4) = q4;
        *(float4*)(pb + 5 * H + lane * 4) = q5;
    }
    __syncthreads();
    for (int o = t; o < 6 * H; o += 1024) {
        int r6 = o >> 8, c = o & 255;
        float v = 0.f;
        #pragma unroll
        for (int ww = 0; ww < 16; ++ww) v += s_part[ww * PS + r6 * H + c];
        if (r6 < 3) aib[(v0 + r6) * H + c] = v;
        else        ajc[(v0 + r6 - 3) * H + c] = v + be1[c];
    }
}

// ============ k_pair: logits + fused row softmax (1024 thr, 4-way h-split) ============
// logits[i,j] = sum_h relu(ai[i,h] + ajc[j,h]) * w2[h]; be2/temp softmax-invariant
__global__ __launch_bounds__(1024) void k_pair(
    const float* __restrict__ aib, const float* __restrict__ ajc,
    const float* __restrict__ We2, float* __restrict__ out) {
    __shared__ __align__(16) float s_ai[3 * H];
    __shared__ __align__(16) float s_w2[H];
    __shared__ float s_acc[3 * 9 * 256];   // quarters 1..3 partials, 27.6 KB
    __shared__ float red[3 * 256];
    const int t = threadIdx.x, b = blockIdx.x;
    const int tc = t & 255, th = t >> 8;
    const int i0 = b * 3;

    if (th == 0) s_w2[tc] = We2[tc];
    else s_ai[(th - 1) * H + tc] = aib[(i0 + th - 1) * H + tc];
    __syncthreads();

    float acc[3][3];
    #pragma unroll
    for (int i = 0; i < 3; ++i)
        #pragma unroll
        for (int jj = 0; jj < 3; ++jj) acc[i][jj] = 0.f;

    const float4* A0 = (const float4*)(ajc + (size_t)tc * H);
    const float4* A1 = (const float4*)(ajc + (size_t)(tc + 256) * H);
    const float4* A2 = (const float4*)(ajc + (size_t)(tc + 512) * H);
    const float4* W4 = (const float4*)s_w2;
    const float4* V0 = (const float4*)s_ai;
    const float4* V1 = (const float4*)(s_ai + 256);
    const float4* V2 = (const float4*)(s_ai + 512);

    const int hbase = th * 16;   // each quarter covers 64 h (16 float4)
    #pragma unroll 4
    for (int q = 0; q < 16; ++q) {
        int h4 = hbase + q;
        float4 w = W4[h4];
        float4 av0 = V0[h4], av1 = V1[h4], av2 = V2[h4];
        float4 b0 = A0[h4], b1 = A1[h4], b2 = A2[h4];
        #define STEP(AV, I)                                                \
            acc[I][0] = fmaf(fmaxf(AV.x + b0.x, 0.f), w.x, acc[I][0]);     \
            acc[I][0] = fmaf(fmaxf(AV.y + b0.y, 0.f), w.y, acc[I][0]);     \
            acc[I][0] = fmaf(fmaxf(AV.z + b0.z, 0.f), w.z, acc[I][0]);     \
            acc[I][0] = fmaf(fmaxf(AV.w + b0.w, 0.f), w.w, acc[I][0]);     \
            acc[I][1] = fmaf(fmaxf(AV.x + b1.x, 0.f), w.x, acc[I][1]);     \
            acc[I][1] = fmaf(fmaxf(AV.y + b1.y, 0.f), w.y, acc[I][1]);     \
            acc[I][1] = fmaf(fmaxf(AV.z + b1.z, 0.f), w.z, acc[I][1]);     \
            acc[I][1] = fmaf(fmaxf(AV.w + b1.w, 0.f), w.w, acc[I][1]);     \
            acc[I][2] = fmaf(fmaxf(AV.x + b2.x, 0.f), w.x, acc[I][2]);     \
            acc[I][2] = fmaf(fmaxf(AV.y + b2.y, 0.f), w.y, acc[I][2]);     \
            acc[I][2] = fmaf(fmaxf(AV.z + b2.z, 0.f), w.z, acc[I][2]);     \
            acc[I][2] = fmaf(fmaxf(AV.w + b2.w, 0.f), w.w, acc[I][2]);
        STEP(av0, 0)
        STEP(av1, 1)
        STEP(av2, 2)
        #undef STEP
    }

    if (th > 0) {
        #pragma unroll
        for (int i = 0; i < 3; ++i)
            #pragma unroll
            for (int jj = 0; jj < 3; ++jj)
                s_acc[((th - 1) * 9 + i * 3 + jj) * 256 + tc] = acc[i][jj];
    }
    __syncthreads();
    if (th == 0) {
        #pragma unroll
        for (int qq = 0; qq < 3; ++qq)
            #pragma unroll
            for (int i = 0; i < 3; ++i)
                #pragma unroll
                for (int jj = 0; jj < 3; ++jj)
                    acc[i][jj] += s_acc[(qq * 9 + i * 3 + jj) * 256 + tc];
        #pragma unroll
        for (int i = 0; i < 3; ++i)
            #pragma unroll
            for (int jj = 0; jj < 3; ++jj)
                if (tc + jj * 256 == i0 + i) acc[i][jj] = -INFINITY;
        #pragma unroll
        for (int i = 0; i < 3; ++i)
            red[i * 256 + tc] = fmaxf(fmaxf(acc[i][0], acc[i][1]), acc[i][2]);
    }
    __syncthreads();
    for (int s = 128; s > 0; s >>= 1) {
        if (t < s) {
            red[t] = fmaxf(red[t], red[t + s]);
            red[256 + t] = fmaxf(red[256 + t], red[256 + t + s]);
            red[512 + t] = fmaxf(red[512 + t], red[512 + t + s]);
        }
        __syncthreads();
    }
    float mx0 = red[0], mx1 = red[256], mx2 = red[512];
    __syncthreads();

    float e[3][3];
    if (th == 0) {
        float s0 = 0.f, s1 = 0.f, s2 = 0.f;
        #pragma unroll
        for (int jj = 0; jj < 3; ++jj) {
            e[0][jj] = __expf(acc[0][jj] - mx0); s0 += e[0][jj];
            e[1][jj] = __expf(acc[1][jj] - mx1); s1 += e[1][jj];
            e[2][jj] = __expf(acc[2][jj] - mx2); s2 += e[2][jj];
        }
        red[tc] = s0; red[256 + tc] = s1; red[512 + tc] = s2;
    }
    __syncthreads();
    for (int s = 128; s > 0; s >>= 1) {
        if (t < s) {
            red[t] += red[t + s];
            red[256 + t] += red[256 + t + s];
            red[512 + t] += red[512 + t + s];
        }
        __syncthreads();
    }
    if (th == 0) {
        float r0 = 1.0f / red[0], r1 = 1.0f / red[256], r2 = 1.0f / red[512];
        #pragma unroll
        for (int jj = 0; jj < 3; ++jj) {
            out[(size_t)(i0 + 0) * N_NODES + tc + jj * 256] = e[0][jj] * r0;
            out[(size_t)(i0 + 1) * N_NODES + tc + jj * 256] = e[1][jj] * r1;
            out[(size_t)(i0 + 2) * N_NODES + tc + jj * 256] = e[2][jj] * r2;
        }
    }
}

extern "C" void kernel_launch(void* const* d_in, const int* in_sizes, int n_in,
                              void* d_out, int out_size, void* d_ws, size_t ws_size,
                              hipStream_t stream) {
    const float* x   = (const float*)d_in[0];
    const int*   ei  = (const int*)d_in[1];
    const float* Wc1 = (const float*)d_in[2];
    const float* bc1 = (const float*)d_in[3];
    const float* Wc2 = (const float*)d_in[4];
    const float* bc2 = (const float*)d_in[5];
    const float* We1 = (const float*)d_in[6];
    const float* be1 = (const float*)d_in[7];
    const float* We2 = (const float*)d_in[8];
    // be2 (d_in[9]) intentionally unused: softmax is shift-invariant.
    float* out = (float*)d_out;

    char* ws = (char*)d_ws;
    int*   cnt   = (int*)(ws + 0);            // 3072
    int*   slots = (int*)(ws + 4096);         // 768*128*4 = 393216
    float* h1    = (float*)(ws + 397312);     // 786432
    float* aib   = (float*)(ws + 1183744);    // 786432
    float* ajc   = (float*)(ws + 1970176);    // 786432

    const int* srcA = ei;             // edge_index[0]
    const int* dstA = ei + N_EDGES;   // edge_index[1]

    k_zero<<<1, 768, 0, stream>>>(cnt);
    k_scatter<<<N_EDGES / 256, 256, 0, stream>>>(srcA, dstA, cnt, slots);
    k_layer1<<<N_NODES, 256, 0, stream>>>(x, Wc1, bc1, cnt, slots, h1);
    k_out<<<N_NODES / 3, 1024, 0, stream>>>(h1, Wc2, bc2, We1, be1, cnt, slots, aib, ajc);
    k_pair<<<N_NODES / 3, 1024, 0, stream>>>(aib, ajc, We2, out);
}

// Round 7
// 65.712 us; speedup vs baseline: 3.4635x; 1.0653x over previous
//
#include <hip/hip_runtime.h>
#include <math.h>

#define N_NODES 768
#define N_EDGES 12288
#define D_INF 6
#define H 256
#define LC 256          // per-block match-list capacity (mean 48, max ~90)
#define PS 1540         // s_part row stride (floats), %32==4 to dodge bank conflicts

// ============ k_h1: self-contained (LDS histogram + edge compact) ->
//              h1 = elu( (A x) Wc1 + bc1 ) for 3 nodes per block ============
__global__ __launch_bounds__(512) void k_h1(
    const float* __restrict__ x, const int* __restrict__ ei,
    const float* __restrict__ Wc1, const float* __restrict__ bc1,
    float* __restrict__ h1) {
    __shared__ int s_cnt[N_NODES];
    __shared__ int s_list[LC];
    __shared__ int s_nm;
    __shared__ float s_agg[3][D_INF];
    const int t = threadIdx.x, b = blockIdx.x;
    const int v0 = b * 3;
    const int* src = ei;
    const int* dst = ei + N_EDGES;

    for (int v = t; v < N_NODES; v += 512) s_cnt[v] = 0;
    if (t == 0) s_nm = 0;
    if (t < 3 * D_INF) ((float*)s_agg)[t] = 0.f;
    __syncthreads();

    for (int e = t; e < N_EDGES; e += 512) {
        int d = dst[e];
        atomicAdd(&s_cnt[d], 1);
        unsigned li = (unsigned)(d - v0);
        if (li < 3u) {
            int p = atomicAdd(&s_nm, 1);
            if (p < LC) s_list[p] = (e << 2) | (int)li;
        }
    }
    __syncthreads();

    const int nm = min(s_nm, LC);
    for (int m = t; m < nm; m += 512) {
        int pk = s_list[m];
        int e = pk >> 2, li = pk & 3;
        int s = src[e];
        float w = rsqrtf((float)(s_cnt[s] + 1)) * rsqrtf((float)(s_cnt[v0 + li] + 1));
        #pragma unroll
        for (int k = 0; k < D_INF; ++k)
            atomicAdd(&s_agg[li][k], w * x[s * D_INF + k]);
    }
    if (t < 3) {   // self-loops
        int v = v0 + t;
        float dv2 = 1.0f / (float)(s_cnt[v] + 1);
        #pragma unroll
        for (int k = 0; k < D_INF; ++k)
            atomicAdd(&s_agg[t][k], dv2 * x[v * D_INF + k]);
    }
    __syncthreads();

    const int tc = t & 255, th = t >> 8;
    for (int r = th; r < 3; r += 2) {
        float acc = bc1[tc];
        #pragma unroll
        for (int k = 0; k < D_INF; ++k)
            acc = fmaf(s_agg[r][k], Wc1[k * H + tc], acc);
        h1[(v0 + r) * H + tc] = (acc > 0.f) ? acc : expm1f(acc);
    }
}

// ============ k_out: self-contained histogram -> agg(h1) -> h2 -> ai / ajcT ============
// ajcT is written TRANSPOSED [H][N_NODES] so k_pair reads are coalesced.
__global__ __launch_bounds__(1024) void k_out(
    const float* __restrict__ h1, const float* __restrict__ Wc2,
    const float* __restrict__ bc2, const float* __restrict__ We1,
    const float* __restrict__ be1, const int* __restrict__ ei,
    float* __restrict__ aib, float* __restrict__ ajcT) {
    __shared__ int s_cnt[N_NODES];                 // 3 KB
    __shared__ int s_list[LC];                     // 1 KB
    __shared__ int s_nm;
    __shared__ float s_agg[3][H];                  // 3 KB
    __shared__ float s_h2[3][H];                   // 3 KB
    __shared__ __align__(16) float s_part[16 * PS];// 98.6 KB
    const int t = threadIdx.x, b = blockIdx.x;
    const int tc = t & 255, th = t >> 8;
    const int w = t >> 6, lane = t & 63;
    const int v0 = b * 3;
    const int* src = ei;
    const int* dst = ei + N_EDGES;

    for (int v = t; v < N_NODES; v += 1024) s_cnt[v] = 0;
    if (t == 0) s_nm = 0;
    __syncthreads();
    for (int e = t; e < N_EDGES; e += 1024) {
        int d = dst[e];
        atomicAdd(&s_cnt[d], 1);
        unsigned li = (unsigned)(d - v0);
        if (li < 3u) {
            int p = atomicAdd(&s_nm, 1);
            if (p < LC) s_list[p] = (e << 2) | (int)li;
        }
    }
    __syncthreads();

    // self-loop init
    if (t < 3 * H) {
        int r = t >> 8;
        float dv2 = 1.0f / (float)(s_cnt[v0 + r] + 1);
        s_agg[r][tc] = dv2 * h1[(v0 + r) * H + tc];
    }
    __syncthreads();

    // neighbor gather: quarter th takes every 4th match
    const int nm = min(s_nm, LC);
    for (int m = th; m < nm; m += 4) {
        int pk = s_list[m];
        int e = pk >> 2, li = pk & 3;
        int s = src[e];
        float wt = rsqrtf((float)(s_cnt[s] + 1)) * rsqrtf((float)(s_cnt[v0 + li] + 1));
        atomicAdd(&s_agg[li][tc], wt * h1[s * H + tc]);
    }
    __syncthreads();

    // ---- phase A: h2 = agg @ Wc2 + bc2, k-split across 16 waves ----
    const int k0 = w * 16;
    {
        float4 a0 = {0.f, 0.f, 0.f, 0.f}, a1 = a0, a2 = a0;
        #pragma unroll
        for (int kk = 0; kk < 16; ++kk) {
            int k = k0 + kk;
            float4 wr = *(const float4*)(Wc2 + (size_t)k * H + lane * 4);
            float g0 = s_agg[0][k], g1 = s_agg[1][k], g2 = s_agg[2][k];
            a0.x = fmaf(g0, wr.x, a0.x); a0.y = fmaf(g0, wr.y, a0.y);
            a0.z = fmaf(g0, wr.z, a0.z); a0.w = fmaf(g0, wr.w, a0.w);
            a1.x = fmaf(g1, wr.x, a1.x); a1.y = fmaf(g1, wr.y, a1.y);
            a1.z = fmaf(g1, wr.z, a1.z); a1.w = fmaf(g1, wr.w, a1.w);
            a2.x = fmaf(g2, wr.x, a2.x); a2.y = fmaf(g2, wr.y, a2.y);
            a2.z = fmaf(g2, wr.z, a2.z); a2.w = fmaf(g2, wr.w, a2.w);
        }
        float* pb = s_part + w * PS;
        *(float4*)(pb + 0 * H + lane * 4) = a0;
        *(float4*)(pb + 1 * H + lane * 4) = a1;
        *(float4*)(pb + 2 * H + lane * 4) = a2;
    }
    __syncthreads();
    if (t < 3 * H) {
        int r = t >> 8;
        float v = bc2[tc];
        #pragma unroll
        for (int ww = 0; ww < 16; ++ww) v += s_part[ww * PS + r * H + tc];
        s_h2[r][tc] = v;
    }
    __syncthreads();

    // ---- phase B: ai = h2 @ We1[:H]; aj = h2 @ We1[H:] + be1 ----
    {
        float4 q0 = {0.f, 0.f, 0.f, 0.f}, q1 = q0, q2 = q0, q3 = q0, q4 = q0, q5 = q0;
        #pragma unroll
        for (int mm = 0; mm < 16; ++mm) {
            int m = k0 + mm;
            float4 wa = *(const float4*)(We1 + (size_t)m * H + lane * 4);
            float4 wb = *(const float4*)(We1 + (size_t)(H + m) * H + lane * 4);
            float g0 = s_h2[0][m], g1 = s_h2[1][m], g2 = s_h2[2][m];
            q0.x = fmaf(g0, wa.x, q0.x); q0.y = fmaf(g0, wa.y, q0.y);
            q0.z = fmaf(g0, wa.z, q0.z); q0.w = fmaf(g0, wa.w, q0.w);
            q1.x = fmaf(g1, wa.x, q1.x); q1.y = fmaf(g1, wa.y, q1.y);
            q1.z = fmaf(g1, wa.z, q1.z); q1.w = fmaf(g1, wa.w, q1.w);
            q2.x = fmaf(g2, wa.x, q2.x); q2.y = fmaf(g2, wa.y, q2.y);
            q2.z = fmaf(g2, wa.z, q2.z); q2.w = fmaf(g2, wa.w, q2.w);
            q3.x = fmaf(g0, wb.x, q3.x); q3.y = fmaf(g0, wb.y, q3.y);
            q3.z = fmaf(g0, wb.z, q3.z); q3.w = fmaf(g0, wb.w, q3.w);
            q4.x = fmaf(g1, wb.x, q4.x); q4.y = fmaf(g1, wb.y, q4.y);
            q4.z = fmaf(g1, wb.z, q4.z); q4.w = fmaf(g1, wb.w, q4.w);
            q5.x = fmaf(g2, wb.x, q5.x); q5.y = fmaf(g2, wb.y, q5.y);
            q5.z = fmaf(g2, wb.z, q5.z); q5.w = fmaf(g2, wb.w, q5.w);
        }
        float* pb = s_part + w * PS;
        *(float4*)(pb + 0 * H + lane * 4) = q0;
        *(float4*)(pb + 1 * H + lane * 4) = q1;
        *(float4*)(pb + 2 * H + lane * 4) = q2;
        *(float4*)(pb + 3 * H + lane * 4) = q3;
        *(float4*)(pb + 4 * H + lane * 4) = q4;
        *(float4*)(pb + 5 * H + lane * 4) = q5;
    }
    __syncthreads();
    for (int o = t; o < 6 * H; o += 1024) {
        int r6 = o >> 8, c = o & 255;
        float v = 0.f;
        #pragma unroll
        for (int ww = 0; ww < 16; ++ww) v += s_part[ww * PS + r6 * H + c];
        if (r6 < 3) aib[(v0 + r6) * H + c] = v;
        else        ajcT[(size_t)c * N_NODES + (v0 + r6 - 3)] = v + be1[c];
    }
}

// ============ k_pair: logits + fused row softmax; ajcT coalesced reads ============
// logits[i,j] = sum_h relu(ai[i,h] + ajcT[h,j]) * w2[h]; be2/temp softmax-invariant
__global__ __launch_bounds__(1024) void k_pair(
    const float* __restrict__ aib, const float* __restrict__ ajcT,
    const float* __restrict__ We2, float* __restrict__ out) {
    __shared__ float s_ai[3 * H];
    __shared__ float s_w2[H];
    __shared__ float s_acc[3 * 9 * 256];   // quarters 1..3 partials
    __shared__ float red[3 * 256];
    const int t = threadIdx.x, b = blockIdx.x;
    const int tc = t & 255, th = t >> 8;
    const int i0 = b * 3;

    if (th == 0) s_w2[tc] = We2[tc];
    else s_ai[(th - 1) * H + tc] = aib[(i0 + th - 1) * H + tc];
    __syncthreads();

    float acc[3][3];
    #pragma unroll
    for (int i = 0; i < 3; ++i)
        #pragma unroll
        for (int jj = 0; jj < 3; ++jj) acc[i][jj] = 0.f;

    const int hb = th * 64;   // each quarter covers 64 h
    #pragma unroll 8
    for (int hh = 0; hh < 64; ++hh) {
        int h = hb + hh;
        float wv = s_w2[h];
        float a0v = s_ai[h], a1v = s_ai[256 + h], a2v = s_ai[512 + h];
        const float* col = ajcT + (size_t)h * N_NODES;
        float b0 = col[tc], b1 = col[tc + 256], b2 = col[tc + 512];
        acc[0][0] = fmaf(fmaxf(a0v + b0, 0.f), wv, acc[0][0]);
        acc[0][1] = fmaf(fmaxf(a0v + b1, 0.f), wv, acc[0][1]);
        acc[0][2] = fmaf(fmaxf(a0v + b2, 0.f), wv, acc[0][2]);
        acc[1][0] = fmaf(fmaxf(a1v + b0, 0.f), wv, acc[1][0]);
        acc[1][1] = fmaf(fmaxf(a1v + b1, 0.f), wv, acc[1][1]);
        acc[1][2] = fmaf(fmaxf(a1v + b2, 0.f), wv, acc[1][2]);
        acc[2][0] = fmaf(fmaxf(a2v + b0, 0.f), wv, acc[2][0]);
        acc[2][1] = fmaf(fmaxf(a2v + b1, 0.f), wv, acc[2][1]);
        acc[2][2] = fmaf(fmaxf(a2v + b2, 0.f), wv, acc[2][2]);
    }

    if (th > 0) {
        #pragma unroll
        for (int i = 0; i < 3; ++i)
            #pragma unroll
            for (int jj = 0; jj < 3; ++jj)
                s_acc[((th - 1) * 9 + i * 3 + jj) * 256 + tc] = acc[i][jj];
    }
    __syncthreads();
    if (th == 0) {
        #pragma unroll
        for (int qq = 0; qq < 3; ++qq)
            #pragma unroll
            for (int i = 0; i < 3; ++i)
                #pragma unroll
                for (int jj = 0; jj < 3; ++jj)
                    acc[i][jj] += s_acc[(qq * 9 + i * 3 + jj) * 256 + tc];
        #pragma unroll
        for (int i = 0; i < 3; ++i)
            #pragma unroll
            for (int jj = 0; jj < 3; ++jj)
                if (tc + jj * 256 == i0 + i) acc[i][jj] = -INFINITY;
        #pragma unroll
        for (int i = 0; i < 3; ++i)
            red[i * 256 + tc] = fmaxf(fmaxf(acc[i][0], acc[i][1]), acc[i][2]);
    }
    __syncthreads();
    for (int s = 128; s > 0; s >>= 1) {
        if (t < s) {
            red[t] = fmaxf(red[t], red[t + s]);
            red[256 + t] = fmaxf(red[256 + t], red[256 + t + s]);
            red[512 + t] = fmaxf(red[512 + t], red[512 + t + s]);
        }
        __syncthreads();
    }
    float mx0 = red[0], mx1 = red[256], mx2 = red[512];
    __syncthreads();

    float e[3][3];
    if (th == 0) {
        float s0 = 0.f, s1 = 0.f, s2 = 0.f;
        #pragma unroll
        for (int jj = 0; jj < 3; ++jj) {
            e[0][jj] = __expf(acc[0][jj] - mx0); s0 += e[0][jj];
            e[1][jj] = __expf(acc[1][jj] - mx1); s1 += e[1][jj];
            e[2][jj] = __expf(acc[2][jj] - mx2); s2 += e[2][jj];
        }
        red[tc] = s0; red[256 + tc] = s1; red[512 + tc] = s2;
    }
    __syncthreads();
    for (int s = 128; s > 0; s >>= 1) {
        if (t < s) {
            red[t] += red[t + s];
            red[256 + t] += red[256 + t + s];
            red[512 + t] += red[512 + t + s];
        }
        __syncthreads();
    }
    if (th == 0) {
        float r0 = 1.0f / red[0], r1 = 1.0f / red[256], r2 = 1.0f / red[512];
        #pragma unroll
        for (int jj = 0; jj < 3; ++jj) {
            out[(size_t)(i0 + 0) * N_NODES + tc + jj * 256] = e[0][jj] * r0;
            out[(size_t)(i0 + 1) * N_NODES + tc + jj * 256] = e[1][jj] * r1;
            out[(size_t)(i0 + 2) * N_NODES + tc + jj * 256] = e[2][jj] * r2;
        }
    }
}

extern "C" void kernel_launch(void* const* d_in, const int* in_sizes, int n_in,
                              void* d_out, int out_size, void* d_ws, size_t ws_size,
                              hipStream_t stream) {
    const float* x   = (const float*)d_in[0];
    const int*   ei  = (const int*)d_in[1];
    const float* Wc1 = (const float*)d_in[2];
    const float* bc1 = (const float*)d_in[3];
    const float* Wc2 = (const float*)d_in[4];
    const float* bc2 = (const float*)d_in[5];
    const float* We1 = (const float*)d_in[6];
    const float* be1 = (const float*)d_in[7];
    const float* We2 = (const float*)d_in[8];
    // be2 (d_in[9]) intentionally unused: softmax is shift-invariant.
    float* out = (float*)d_out;

    char* ws = (char*)d_ws;
    float* h1   = (float*)(ws + 0);          // 786432
    float* aib  = (float*)(ws + 786432);     // 786432
    float* ajcT = (float*)(ws + 1572864);    // 786432  [H][N_NODES]

    k_h1<<<N_NODES / 3, 512, 0, stream>>>(x, ei, Wc1, bc1, h1);
    k_out<<<N_NODES / 3, 1024, 0, stream>>>(h1, Wc2, bc2, We1, be1, ei, aib, ajcT);
    k_pair<<<N_NODES / 3, 1024, 0, stream>>>(aib, ajcT, We2, out);
}

// Round 8
// 65.059 us; speedup vs baseline: 3.4982x; 1.0100x over previous
//
#include <hip/hip_runtime.h>
#include <math.h>

#define N_NODES 768
#define N_EDGES 12288
#define D_INF 6
#define H 256
#define CAP 128     // bucket capacity per node
#define SA 260      // LDS row stride (floats): %4==0 for float4, %32==4 for banks

// ============ k_zero ============
__global__ __launch_bounds__(768) void k_zero(int* __restrict__ cnt) {
    cnt[threadIdx.x] = 0;
}

// ============ k_scatter: bucket edges by dst ============
__global__ void k_scatter(const int* __restrict__ src, const int* __restrict__ dst,
                          int* __restrict__ cnt, int* __restrict__ slots) {
    int e = blockIdx.x * blockDim.x + threadIdx.x;
    if (e >= N_EDGES) return;
    int d = dst[e];
    int p = atomicAdd(&cnt[d], 1);
    if (p < CAP) slots[d * CAP + p] = src[e];
}

// ============ k_layer1: h1 = elu( (A x) Wc1 + bc1 ), 1 node/block ============
__global__ __launch_bounds__(256) void k_layer1(
    const float* __restrict__ x, const float* __restrict__ Wc1,
    const float* __restrict__ bc1, const int* __restrict__ cnt,
    const int* __restrict__ slots, float* __restrict__ h1) {
    __shared__ float s6[8];
    const int v = blockIdx.x, t = threadIdx.x;
    const int c = cnt[v];
    const float dv = rsqrtf((float)(c + 1));
    if (t < 64) {
        float a[D_INF] = {0.f, 0.f, 0.f, 0.f, 0.f, 0.f};
        if (t == 0) {
            float w = dv * dv;
            #pragma unroll
            for (int k = 0; k < D_INF; ++k) a[k] = w * x[v * D_INF + k];
        }
        for (int n = t; n < c; n += 64) {
            int s = slots[v * CAP + n];
            float w = rsqrtf((float)(cnt[s] + 1)) * dv;
            #pragma unroll
            for (int k = 0; k < D_INF; ++k) a[k] = fmaf(w, x[s * D_INF + k], a[k]);
        }
        #pragma unroll
        for (int m = 32; m >= 1; m >>= 1) {
            #pragma unroll
            for (int k = 0; k < D_INF; ++k) a[k] += __shfl_xor(a[k], m, 64);
        }
        if (t == 0) {
            #pragma unroll
            for (int k = 0; k < D_INF; ++k) s6[k] = a[k];
        }
    }
    __syncthreads();
    float acc = bc1[t];
    #pragma unroll
    for (int k = 0; k < D_INF; ++k) acc = fmaf(s6[k], Wc1[k * H + t], acc);
    h1[v * H + t] = (acc > 0.f) ? acc : expm1f(acc);
}

// ============ k_agg: agg2 = (A h1), 3 nodes/block ============
__global__ __launch_bounds__(256) void k_agg(
    const float* __restrict__ h1, const int* __restrict__ cnt,
    const int* __restrict__ slots, float* __restrict__ agg2) {
    const int t = threadIdx.x, b = blockIdx.x;
    #pragma unroll
    for (int r = 0; r < 3; ++r) {
        int v = b * 3 + r;
        int c = cnt[v];
        float dv = rsqrtf((float)(c + 1));
        float acc = dv * dv * h1[v * H + t];
        #pragma unroll 2
        for (int n = 0; n < c; ++n) {
            int s = slots[v * CAP + n];
            float w = rsqrtf((float)(cnt[s] + 1)) * dv;
            acc = fmaf(w, h1[s * H + t], acc);
        }
        agg2[v * H + t] = acc;
    }
}

// ============ k_h2: h2 = agg2 @ Wc2 + bc2 (panel-tiled GEMM) ============
// grid 256 = 16 row-groups (48 rows) x 16 col-panels (16 cols)
__global__ __launch_bounds__(256) void k_h2(
    const float* __restrict__ agg2, const float* __restrict__ Wc2,
    const float* __restrict__ bc2, float* __restrict__ h2) {
    __shared__ __align__(16) float s_a[48 * SA];    // 49.9 KB
    __shared__ __align__(16) float s_wT[16 * SA];   // 16.6 KB
    const int t = threadIdx.x, b = blockIdx.x;
    const int rg = b >> 4, cp = b & 15;
    const int j0 = rg * 48, c0 = cp * 16;
    const int c = t & 15, ro = t >> 4;

    // stage A-tile (48 rows x 256) coalesced
    for (int i = t; i < 48 * 64; i += 256) {
        int r = i >> 6, q = i & 63;
        float4 v = *(const float4*)(agg2 + (size_t)(j0 + r) * H + q * 4);
        *(float4*)&s_a[r * SA + q * 4] = v;
    }
    // stage weight panel transposed: s_wT[c][k] = Wc2[k][c0+c]
    {
        int kk = t >> 4, cc = t & 15;
        #pragma unroll
        for (int it = 0; it < 16; ++it) {
            int k = kk + it * 16;
            s_wT[cc * SA + k] = Wc2[(size_t)k * H + c0 + cc];
        }
    }
    __syncthreads();

    float a0 = 0.f, a1 = 0.f, a2 = 0.f;
    #pragma unroll 8
    for (int kg = 0; kg < 64; ++kg) {
        float4 w  = *(const float4*)&s_wT[c * SA + kg * 4];
        float4 v0 = *(const float4*)&s_a[(ro)      * SA + kg * 4];
        float4 v1 = *(const float4*)&s_a[(ro + 16) * SA + kg * 4];
        float4 v2 = *(const float4*)&s_a[(ro + 32) * SA + kg * 4];
        a0 = fmaf(v0.x, w.x, a0); a0 = fmaf(v0.y, w.y, a0);
        a0 = fmaf(v0.z, w.z, a0); a0 = fmaf(v0.w, w.w, a0);
        a1 = fmaf(v1.x, w.x, a1); a1 = fmaf(v1.y, w.y, a1);
        a1 = fmaf(v1.z, w.z, a1); a1 = fmaf(v1.w, w.w, a1);
        a2 = fmaf(v2.x, w.x, a2); a2 = fmaf(v2.y, w.y, a2);
        a2 = fmaf(v2.z, w.z, a2); a2 = fmaf(v2.w, w.w, a2);
    }
    float bb = bc2[c0 + c];
    h2[(size_t)(j0 + ro)      * H + c0 + c] = a0 + bb;
    h2[(size_t)(j0 + ro + 16) * H + c0 + c] = a1 + bb;
    h2[(size_t)(j0 + ro + 32) * H + c0 + c] = a2 + bb;
}

// ============ k_ae: ai = h2@We1[:H]; ajT = (h2@We1[H:] + be1)^T ============
// grid 384 = 24 row-groups (32 rows) x 16 col-panels (16 cols)
__global__ __launch_bounds__(256) void k_ae(
    const float* __restrict__ h2, const float* __restrict__ We1,
    const float* __restrict__ be1, float* __restrict__ aib,
    float* __restrict__ ajcT) {
    __shared__ __align__(16) float s_h[32 * SA];     // 33.3 KB
    __shared__ __align__(16) float s_waT[16 * SA];   // 16.6 KB
    __shared__ __align__(16) float s_wbT[16 * SA];   // 16.6 KB
    const int t = threadIdx.x, b = blockIdx.x;
    const int rg = b >> 4, cp = b & 15;
    const int j0 = rg * 32, c0 = cp * 16;
    const int c = t & 15, ro = t >> 4;

    for (int i = t; i < 32 * 64; i += 256) {
        int r = i >> 6, q = i & 63;
        float4 v = *(const float4*)(h2 + (size_t)(j0 + r) * H + q * 4);
        *(float4*)&s_h[r * SA + q * 4] = v;
    }
    {
        int kk = t >> 4, cc = t & 15;
        #pragma unroll
        for (int it = 0; it < 16; ++it) {
            int k = kk + it * 16;
            s_waT[cc * SA + k] = We1[(size_t)k * H + c0 + cc];
            s_wbT[cc * SA + k] = We1[(size_t)(H + k) * H + c0 + cc];
        }
    }
    __syncthreads();

    float pa0 = 0.f, pa1 = 0.f, pb0 = 0.f, pb1 = 0.f;
    #pragma unroll 8
    for (int kg = 0; kg < 64; ++kg) {
        float4 wa = *(const float4*)&s_waT[c * SA + kg * 4];
        float4 wb = *(const float4*)&s_wbT[c * SA + kg * 4];
        float4 v0 = *(const float4*)&s_h[(ro)      * SA + kg * 4];
        float4 v1 = *(const float4*)&s_h[(ro + 16) * SA + kg * 4];
        pa0 = fmaf(v0.x, wa.x, pa0); pa0 = fmaf(v0.y, wa.y, pa0);
        pa0 = fmaf(v0.z, wa.z, pa0); pa0 = fmaf(v0.w, wa.w, pa0);
        pa1 = fmaf(v1.x, wa.x, pa1); pa1 = fmaf(v1.y, wa.y, pa1);
        pa1 = fmaf(v1.z, wa.z, pa1); pa1 = fmaf(v1.w, wa.w, pa1);
        pb0 = fmaf(v0.x, wb.x, pb0); pb0 = fmaf(v0.y, wb.y, pb0);
        pb0 = fmaf(v0.z, wb.z, pb0); pb0 = fmaf(v0.w, wb.w, pb0);
        pb1 = fmaf(v1.x, wb.x, pb1); pb1 = fmaf(v1.y, wb.y, pb1);
        pb1 = fmaf(v1.z, wb.z, pb1); pb1 = fmaf(v1.w, wb.w, pb1);
    }
    aib[(size_t)(j0 + ro)      * H + c0 + c] = pa0;
    aib[(size_t)(j0 + ro + 16) * H + c0 + c] = pa1;
    float be = be1[c0 + c];
    // transposed write: full-line chunks (32 consecutive j per h), no false sharing
    ajcT[(size_t)(c0 + c) * N_NODES + j0 + ro]      = pb0 + be;
    ajcT[(size_t)(c0 + c) * N_NODES + j0 + ro + 16] = pb1 + be;
}

// ============ k_pair: logits + fused row softmax; ajcT coalesced reads ============
__global__ __launch_bounds__(1024) void k_pair(
    const float* __restrict__ aib, const float* __restrict__ ajcT,
    const float* __restrict__ We2, float* __restrict__ out) {
    __shared__ float s_ai[3 * H];
    __shared__ float s_w2[H];
    __shared__ float s_acc[3 * 9 * 256];
    __shared__ float red[3 * 256];
    const int t = threadIdx.x, b = blockIdx.x;
    const int tc = t & 255, th = t >> 8;
    const int i0 = b * 3;

    if (th == 0) s_w2[tc] = We2[tc];
    else s_ai[(th - 1) * H + tc] = aib[(i0 + th - 1) * H + tc];
    __syncthreads();

    float acc[3][3];
    #pragma unroll
    for (int i = 0; i < 3; ++i)
        #pragma unroll
        for (int jj = 0; jj < 3; ++jj) acc[i][jj] = 0.f;

    const int hb = th * 64;
    #pragma unroll 8
    for (int hh = 0; hh < 64; ++hh) {
        int h = hb + hh;
        float wv = s_w2[h];
        float a0v = s_ai[h], a1v = s_ai[256 + h], a2v = s_ai[512 + h];
        const float* col = ajcT + (size_t)h * N_NODES;
        float b0 = col[tc], b1 = col[tc + 256], b2 = col[tc + 512];
        acc[0][0] = fmaf(fmaxf(a0v + b0, 0.f), wv, acc[0][0]);
        acc[0][1] = fmaf(fmaxf(a0v + b1, 0.f), wv, acc[0][1]);
        acc[0][2] = fmaf(fmaxf(a0v + b2, 0.f), wv, acc[0][2]);
        acc[1][0] = fmaf(fmaxf(a1v + b0, 0.f), wv, acc[1][0]);
        acc[1][1] = fmaf(fmaxf(a1v + b1, 0.f), wv, acc[1][1]);
        acc[1][2] = fmaf(fmaxf(a1v + b2, 0.f), wv, acc[1][2]);
        acc[2][0] = fmaf(fmaxf(a2v + b0, 0.f), wv, acc[2][0]);
        acc[2][1] = fmaf(fmaxf(a2v + b1, 0.f), wv, acc[2][1]);
        acc[2][2] = fmaf(fmaxf(a2v + b2, 0.f), wv, acc[2][2]);
    }

    if (th > 0) {
        #pragma unroll
        for (int i = 0; i < 3; ++i)
            #pragma unroll
            for (int jj = 0; jj < 3; ++jj)
                s_acc[((th - 1) * 9 + i * 3 + jj) * 256 + tc] = acc[i][jj];
    }
    __syncthreads();
    if (th == 0) {
        #pragma unroll
        for (int qq = 0; qq < 3; ++qq)
            #pragma unroll
            for (int i = 0; i < 3; ++i)
                #pragma unroll
                for (int jj = 0; jj < 3; ++jj)
                    acc[i][jj] += s_acc[(qq * 9 + i * 3 + jj) * 256 + tc];
        #pragma unroll
        for (int i = 0; i < 3; ++i)
            #pragma unroll
            for (int jj = 0; jj < 3; ++jj)
                if (tc + jj * 256 == i0 + i) acc[i][jj] = -INFINITY;
        #pragma unroll
        for (int i = 0; i < 3; ++i)
            red[i * 256 + tc] = fmaxf(fmaxf(acc[i][0], acc[i][1]), acc[i][2]);
    }
    __syncthreads();
    for (int s = 128; s > 0; s >>= 1) {
        if (t < s) {
            red[t] = fmaxf(red[t], red[t + s]);
            red[256 + t] = fmaxf(red[256 + t], red[256 + t + s]);
            red[512 + t] = fmaxf(red[512 + t], red[512 + t + s]);
        }
        __syncthreads();
    }
    float mx0 = red[0], mx1 = red[256], mx2 = red[512];
    __syncthreads();

    float e[3][3];
    if (th == 0) {
        float s0 = 0.f, s1 = 0.f, s2 = 0.f;
        #pragma unroll
        for (int jj = 0; jj < 3; ++jj) {
            e[0][jj] = __expf(acc[0][jj] - mx0); s0 += e[0][jj];
            e[1][jj] = __expf(acc[1][jj] - mx1); s1 += e[1][jj];
            e[2][jj] = __expf(acc[2][jj] - mx2); s2 += e[2][jj];
        }
        red[tc] = s0; red[256 + tc] = s1; red[512 + tc] = s2;
    }
    __syncthreads();
    for (int s = 128; s > 0; s >>= 1) {
        if (t < s) {
            red[t] += red[t + s];
            red[256 + t] += red[256 + t + s];
            red[512 + t] += red[512 + t + s];
        }
        __syncthreads();
    }
    if (th == 0) {
        float r0 = 1.0f / red[0], r1 = 1.0f / red[256], r2 = 1.0f / red[512];
        #pragma unroll
        for (int jj = 0; jj < 3; ++jj) {
            out[(size_t)(i0 + 0) * N_NODES + tc + jj * 256] = e[0][jj] * r0;
            out[(size_t)(i0 + 1) * N_NODES + tc + jj * 256] = e[1][jj] * r1;
            out[(size_t)(i0 + 2) * N_NODES + tc + jj * 256] = e[2][jj] * r2;
        }
    }
}

extern "C" void kernel_launch(void* const* d_in, const int* in_sizes, int n_in,
                              void* d_out, int out_size, void* d_ws, size_t ws_size,
                              hipStream_t stream) {
    const float* x   = (const float*)d_in[0];
    const int*   ei  = (const int*)d_in[1];
    const float* Wc1 = (const float*)d_in[2];
    const float* bc1 = (const float*)d_in[3];
    const float* Wc2 = (const float*)d_in[4];
    const float* bc2 = (const float*)d_in[5];
    const float* We1 = (const float*)d_in[6];
    const float* be1 = (const float*)d_in[7];
    const float* We2 = (const float*)d_in[8];
    // be2 (d_in[9]) unused: softmax shift-invariant.
    float* out = (float*)d_out;

    char* ws = (char*)d_ws;
    int*   cnt   = (int*)(ws + 0);            // 3072
    int*   slots = (int*)(ws + 4096);         // 393216
    float* h1    = (float*)(ws + 397312);     // 786432 (reused as h2's src is agg2)
    float* agg2  = (float*)(ws + 1183744);    // 786432
    float* ajcT  = (float*)(ws + 1970176);    // 786432
    float* h2    = h1;      // h1 dead after k_agg
    float* aib   = agg2;    // agg2 dead after k_h2

    const int* srcA = ei;
    const int* dstA = ei + N_EDGES;

    k_zero<<<1, 768, 0, stream>>>(cnt);
    k_scatter<<<N_EDGES / 256, 256, 0, stream>>>(srcA, dstA, cnt, slots);
    k_layer1<<<N_NODES, 256, 0, stream>>>(x, Wc1, bc1, cnt, slots, h1);
    k_agg<<<N_NODES / 3, 256, 0, stream>>>(h1, cnt, slots, agg2);
    k_h2<<<256, 256, 0, stream>>>(agg2, Wc2, bc2, h2);
    k_ae<<<384, 256, 0, stream>>>(h2, We1, be1, aib, ajcT);
    k_pair<<<N_NODES / 3, 1024, 0, stream>>>(aib, ajcT, We2, out);
}

// Round 9
// 58.618 us; speedup vs baseline: 3.8827x; 1.1099x over previous
//
#include <hip/hip_runtime.h>
#include <math.h>

#define N_NODES 768
#define N_EDGES 12288
#define D_INF 6
#define H 256
#define CAP 128     // bucket capacity per node
#define SA 260      // LDS row stride (floats): %4==0 for float4, %32==4 for banks

// ============ k_zero ============
__global__ __launch_bounds__(768) void k_zero(int* __restrict__ cnt) {
    cnt[threadIdx.x] = 0;
}

// ============ k_scatter: bucket edges by dst ============
__global__ void k_scatter(const int* __restrict__ src, const int* __restrict__ dst,
                          int* __restrict__ cnt, int* __restrict__ slots) {
    int e = blockIdx.x * blockDim.x + threadIdx.x;
    if (e >= N_EDGES) return;
    int d = dst[e];
    int p = atomicAdd(&cnt[d], 1);
    if (p < CAP) slots[d * CAP + p] = src[e];
}

// ============ k_layer1: h1 = elu( (A x) Wc1 + bc1 ), 1 node/block ============
// (s,w) preloaded in PARALLEL (independent loads) -> no serial dep chain
__global__ __launch_bounds__(256) void k_layer1(
    const float* __restrict__ x, const float* __restrict__ Wc1,
    const float* __restrict__ bc1, const int* __restrict__ cnt,
    const int* __restrict__ slots, float* __restrict__ h1) {
    __shared__ int   s_s[CAP];
    __shared__ float s_w[CAP];
    __shared__ float s6[D_INF];
    const int v = blockIdx.x, t = threadIdx.x;
    const int c = cnt[v];
    const int cc = min(c, CAP);
    const float dv = rsqrtf((float)(c + 1));

    if (t < D_INF) s6[t] = dv * dv * x[v * D_INF + t];   // self-loop
    for (int i = t; i < cc; i += 256) {
        int s = slots[v * CAP + i];
        s_s[i] = s;
        s_w[i] = rsqrtf((float)(cnt[s] + 1)) * dv;
    }
    __syncthreads();
    // parallel gather: thread (n,k) adds w_n * x[s_n][k]
    for (int i = t; i < D_INF * cc; i += 256) {
        int n = i / D_INF, k = i - n * D_INF;
        atomicAdd(&s6[k], s_w[n] * x[s_s[n] * D_INF + k]);
    }
    __syncthreads();
    float acc = bc1[t];
    #pragma unroll
    for (int k = 0; k < D_INF; ++k) acc = fmaf(s6[k], Wc1[k * H + t], acc);
    h1[v * H + t] = (acc > 0.f) ? acc : expm1f(acc);
}

// ============ k_agg: agg2 = (A h1), 1 node/block, (s,w) preloaded ============
__global__ __launch_bounds__(256) void k_agg(
    const float* __restrict__ h1, const int* __restrict__ cnt,
    const int* __restrict__ slots, float* __restrict__ agg2) {
    __shared__ int   s_s[CAP];
    __shared__ float s_w[CAP];
    const int v = blockIdx.x, t = threadIdx.x;
    const int c = cnt[v];
    const int cc = min(c, CAP);
    const float dv = rsqrtf((float)(c + 1));

    for (int i = t; i < cc; i += 256) {          // independent parallel loads
        int s = slots[v * CAP + i];
        s_s[i] = s;
        s_w[i] = rsqrtf((float)(cnt[s] + 1)) * dv;
    }
    __syncthreads();
    float acc = dv * dv * h1[v * H + t];          // self-loop
    #pragma unroll 4
    for (int n = 0; n < cc; ++n)                  // h1-row loads independent -> pipeline
        acc = fmaf(s_w[n], h1[s_s[n] * H + t], acc);
    agg2[v * H + t] = acc;
}

// ============ k_h2: h2 = agg2 @ Wc2 + bc2 (panel-tiled GEMM) ============
// grid 256 = 16 row-groups (48 rows) x 16 col-panels (16 cols)
__global__ __launch_bounds__(256) void k_h2(
    const float* __restrict__ agg2, const float* __restrict__ Wc2,
    const float* __restrict__ bc2, float* __restrict__ h2) {
    __shared__ __align__(16) float s_a[48 * SA];    // 49.9 KB
    __shared__ __align__(16) float s_wT[16 * SA];   // 16.6 KB
    const int t = threadIdx.x, b = blockIdx.x;
    const int rg = b >> 4, cp = b & 15;
    const int j0 = rg * 48, c0 = cp * 16;
    const int c = t & 15, ro = t >> 4;

    for (int i = t; i < 48 * 64; i += 256) {
        int r = i >> 6, q = i & 63;
        float4 v = *(const float4*)(agg2 + (size_t)(j0 + r) * H + q * 4);
        *(float4*)&s_a[r * SA + q * 4] = v;
    }
    {
        int kk = t >> 4, cc = t & 15;
        #pragma unroll
        for (int it = 0; it < 16; ++it) {
            int k = kk + it * 16;
            s_wT[cc * SA + k] = Wc2[(size_t)k * H + c0 + cc];
        }
    }
    __syncthreads();

    float a0 = 0.f, a1 = 0.f, a2 = 0.f;
    #pragma unroll 8
    for (int kg = 0; kg < 64; ++kg) {
        float4 w  = *(const float4*)&s_wT[c * SA + kg * 4];
        float4 v0 = *(const float4*)&s_a[(ro)      * SA + kg * 4];
        float4 v1 = *(const float4*)&s_a[(ro + 16) * SA + kg * 4];
        float4 v2 = *(const float4*)&s_a[(ro + 32) * SA + kg * 4];
        a0 = fmaf(v0.x, w.x, a0); a0 = fmaf(v0.y, w.y, a0);
        a0 = fmaf(v0.z, w.z, a0); a0 = fmaf(v0.w, w.w, a0);
        a1 = fmaf(v1.x, w.x, a1); a1 = fmaf(v1.y, w.y, a1);
        a1 = fmaf(v1.z, w.z, a1); a1 = fmaf(v1.w, w.w, a1);
        a2 = fmaf(v2.x, w.x, a2); a2 = fmaf(v2.y, w.y, a2);
        a2 = fmaf(v2.z, w.z, a2); a2 = fmaf(v2.w, w.w, a2);
    }
    float bb = bc2[c0 + c];
    h2[(size_t)(j0 + ro)      * H + c0 + c] = a0 + bb;
    h2[(size_t)(j0 + ro + 16) * H + c0 + c] = a1 + bb;
    h2[(size_t)(j0 + ro + 32) * H + c0 + c] = a2 + bb;
}

// ============ k_ae: ai = h2@We1[:H]; ajT = (h2@We1[H:] + be1)^T ============
// grid 384 = 24 row-groups (32 rows) x 16 col-panels (16 cols)
__global__ __launch_bounds__(256) void k_ae(
    const float* __restrict__ h2, const float* __restrict__ We1,
    const float* __restrict__ be1, float* __restrict__ aib,
    float* __restrict__ ajcT) {
    __shared__ __align__(16) float s_h[32 * SA];     // 33.3 KB
    __shared__ __align__(16) float s_waT[16 * SA];   // 16.6 KB
    __shared__ __align__(16) float s_wbT[16 * SA];   // 16.6 KB
    const int t = threadIdx.x, b = blockIdx.x;
    const int rg = b >> 4, cp = b & 15;
    const int j0 = rg * 32, c0 = cp * 16;
    const int c = t & 15, ro = t >> 4;

    for (int i = t; i < 32 * 64; i += 256) {
        int r = i >> 6, q = i & 63;
        float4 v = *(const float4*)(h2 + (size_t)(j0 + r) * H + q * 4);
        *(float4*)&s_h[r * SA + q * 4] = v;
    }
    {
        int kk = t >> 4, cc = t & 15;
        #pragma unroll
        for (int it = 0; it < 16; ++it) {
            int k = kk + it * 16;
            s_waT[cc * SA + k] = We1[(size_t)k * H + c0 + cc];
            s_wbT[cc * SA + k] = We1[(size_t)(H + k) * H + c0 + cc];
        }
    }
    __syncthreads();

    float pa0 = 0.f, pa1 = 0.f, pb0 = 0.f, pb1 = 0.f;
    #pragma unroll 8
    for (int kg = 0; kg < 64; ++kg) {
        float4 wa = *(const float4*)&s_waT[c * SA + kg * 4];
        float4 wb = *(const float4*)&s_wbT[c * SA + kg * 4];
        float4 v0 = *(const float4*)&s_h[(ro)      * SA + kg * 4];
        float4 v1 = *(const float4*)&s_h[(ro + 16) * SA + kg * 4];
        pa0 = fmaf(v0.x, wa.x, pa0); pa0 = fmaf(v0.y, wa.y, pa0);
        pa0 = fmaf(v0.z, wa.z, pa0); pa0 = fmaf(v0.w, wa.w, pa0);
        pa1 = fmaf(v1.x, wa.x, pa1); pa1 = fmaf(v1.y, wa.y, pa1);
        pa1 = fmaf(v1.z, wa.z, pa1); pa1 = fmaf(v1.w, wa.w, pa1);
        pb0 = fmaf(v0.x, wb.x, pb0); pb0 = fmaf(v0.y, wb.y, pb0);
        pb0 = fmaf(v0.z, wb.z, pb0); pb0 = fmaf(v0.w, wb.w, pb0);
        pb1 = fmaf(v1.x, wb.x, pb1); pb1 = fmaf(v1.y, wb.y, pb1);
        pb1 = fmaf(v1.z, wb.z, pb1); pb1 = fmaf(v1.w, wb.w, pb1);
    }
    aib[(size_t)(j0 + ro)      * H + c0 + c] = pa0;
    aib[(size_t)(j0 + ro + 16) * H + c0 + c] = pa1;
    float be = be1[c0 + c];
    ajcT[(size_t)(c0 + c) * N_NODES + j0 + ro]      = pb0 + be;
    ajcT[(size_t)(c0 + c) * N_NODES + j0 + ro + 16] = pb1 + be;
}

// ============ k_pair: logits + fused row softmax; ajcT coalesced reads ============
__global__ __launch_bounds__(1024) void k_pair(
    const float* __restrict__ aib, const float* __restrict__ ajcT,
    const float* __restrict__ We2, float* __restrict__ out) {
    __shared__ float s_ai[3 * H];
    __shared__ float s_w2[H];
    __shared__ float s_acc[3 * 9 * 256];
    __shared__ float red[3 * 256];
    const int t = threadIdx.x, b = blockIdx.x;
    const int tc = t & 255, th = t >> 8;
    const int i0 = b * 3;

    if (th == 0) s_w2[tc] = We2[tc];
    else s_ai[(th - 1) * H + tc] = aib[(i0 + th - 1) * H + tc];
    __syncthreads();

    float acc[3][3];
    #pragma unroll
    for (int i = 0; i < 3; ++i)
        #pragma unroll
        for (int jj = 0; jj < 3; ++jj) acc[i][jj] = 0.f;

    const int hb = th * 64;
    #pragma unroll 8
    for (int hh = 0; hh < 64; ++hh) {
        int h = hb + hh;
        float wv = s_w2[h];
        float a0v = s_ai[h], a1v = s_ai[256 + h], a2v = s_ai[512 + h];
        const float* col = ajcT + (size_t)h * N_NODES;
        float b0 = col[tc], b1 = col[tc + 256], b2 = col[tc + 512];
        acc[0][0] = fmaf(fmaxf(a0v + b0, 0.f), wv, acc[0][0]);
        acc[0][1] = fmaf(fmaxf(a0v + b1, 0.f), wv, acc[0][1]);
        acc[0][2] = fmaf(fmaxf(a0v + b2, 0.f), wv, acc[0][2]);
        acc[1][0] = fmaf(fmaxf(a1v + b0, 0.f), wv, acc[1][0]);
        acc[1][1] = fmaf(fmaxf(a1v + b1, 0.f), wv, acc[1][1]);
        acc[1][2] = fmaf(fmaxf(a1v + b2, 0.f), wv, acc[1][2]);
        acc[2][0] = fmaf(fmaxf(a2v + b0, 0.f), wv, acc[2][0]);
        acc[2][1] = fmaf(fmaxf(a2v + b1, 0.f), wv, acc[2][1]);
        acc[2][2] = fmaf(fmaxf(a2v + b2, 0.f), wv, acc[2][2]);
    }

    if (th > 0) {
        #pragma unroll
        for (int i = 0; i < 3; ++i)
            #pragma unroll
            for (int jj = 0; jj < 3; ++jj)
                s_acc[((th - 1) * 9 + i * 3 + jj) * 256 + tc] = acc[i][jj];
    }
    __syncthreads();
    if (th == 0) {
        #pragma unroll
        for (int qq = 0; qq < 3; ++qq)
            #pragma unroll
            for (int i = 0; i < 3; ++i)
                #pragma unroll
                for (int jj = 0; jj < 3; ++jj)
                    acc[i][jj] += s_acc[(qq * 9 + i * 3 + jj) * 256 + tc];
        #pragma unroll
        for (int i = 0; i < 3; ++i)
            #pragma unroll
            for (int jj = 0; jj < 3; ++jj)
                if (tc + jj * 256 == i0 + i) acc[i][jj] = -INFINITY;
        #pragma unroll
        for (int i = 0; i < 3; ++i)
            red[i * 256 + tc] = fmaxf(fmaxf(acc[i][0], acc[i][1]), acc[i][2]);
    }
    __syncthreads();
    for (int s = 128; s > 0; s >>= 1) {
        if (t < s) {
            red[t] = fmaxf(red[t], red[t + s]);
            red[256 + t] = fmaxf(red[256 + t], red[256 + t + s]);
            red[512 + t] = fmaxf(red[512 + t], red[512 + t + s]);
        }
        __syncthreads();
    }
    float mx0 = red[0], mx1 = red[256], mx2 = red[512];
    __syncthreads();

    float e[3][3];
    if (th == 0) {
        float s0 = 0.f, s1 = 0.f, s2 = 0.f;
        #pragma unroll
        for (int jj = 0; jj < 3; ++jj) {
            e[0][jj] = __expf(acc[0][jj] - mx0); s0 += e[0][jj];
            e[1][jj] = __expf(acc[1][jj] - mx1); s1 += e[1][jj];
            e[2][jj] = __expf(acc[2][jj] - mx2); s2 += e[2][jj];
        }
        red[tc] = s0; red[256 + tc] = s1; red[512 + tc] = s2;
    }
    __syncthreads();
    for (int s = 128; s > 0; s >>= 1) {
        if (t < s) {
            red[t] += red[t + s];
            red[256 + t] += red[256 + t + s];
            red[512 + t] += red[512 + t + s];
        }
        __syncthreads();
    }
    if (th == 0) {
        float r0 = 1.0f / red[0], r1 = 1.0f / red[256], r2 = 1.0f / red[512];
        #pragma unroll
        for (int jj = 0; jj < 3; ++jj) {
            out[(size_t)(i0 + 0) * N_NODES + tc + jj * 256] = e[0][jj] * r0;
            out[(size_t)(i0 + 1) * N_NODES + tc + jj * 256] = e[1][jj] * r1;
            out[(size_t)(i0 + 2) * N_NODES + tc + jj * 256] = e[2][jj] * r2;
        }
    }
}

extern "C" void kernel_launch(void* const* d_in, const int* in_sizes, int n_in,
                              void* d_out, int out_size, void* d_ws, size_t ws_size,
                              hipStream_t stream) {
    const float* x   = (const float*)d_in[0];
    const int*   ei  = (const int*)d_in[1];
    const float* Wc1 = (const float*)d_in[2];
    const float* bc1 = (const float*)d_in[3];
    const float* Wc2 = (const float*)d_in[4];
    const float* bc2 = (const float*)d_in[5];
    const float* We1 = (const float*)d_in[6];
    const float* be1 = (const float*)d_in[7];
    const float* We2 = (const float*)d_in[8];
    // be2 (d_in[9]) unused: softmax shift-invariant.
    float* out = (float*)d_out;

    char* ws = (char*)d_ws;
    int*   cnt   = (int*)(ws + 0);            // 3072
    int*   slots = (int*)(ws + 4096);         // 393216
    float* h1    = (float*)(ws + 397312);     // 786432
    float* agg2  = (float*)(ws + 1183744);    // 786432
    float* ajcT  = (float*)(ws + 1970176);    // 786432
    float* h2    = h1;      // h1 dead after k_agg
    float* aib   = agg2;    // agg2 dead after k_h2

    const int* srcA = ei;
    const int* dstA = ei + N_EDGES;

    k_zero<<<1, 768, 0, stream>>>(cnt);
    k_scatter<<<N_EDGES / 256, 256, 0, stream>>>(srcA, dstA, cnt, slots);
    k_layer1<<<N_NODES, 256, 0, stream>>>(x, Wc1, bc1, cnt, slots, h1);
    k_agg<<<N_NODES, 256, 0, stream>>>(h1, cnt, slots, agg2);
    k_h2<<<256, 256, 0, stream>>>(agg2, Wc2, bc2, h2);
    k_ae<<<384, 256, 0, stream>>>(h2, We1, be1, aib, ajcT);
    k_pair<<<N_NODES / 3, 1024, 0, stream>>>(aib, ajcT, We2, out);
}

// Round 10
// 57.302 us; speedup vs baseline: 3.9718x; 1.0230x over previous
//
#include <hip/hip_runtime.h>
#include <math.h>

#define N_NODES 768
#define N_EDGES 12288
#define D_INF 6
#define H 256
#define H2 512
#define CAP 128     // slots per node
#define LC 256      // per-3-node match list cap (mean 48)
#define SA 260      // LDS row stride: %4==0 for float4, %32==4 for banks

// ================= K1 k_front: heterogeneous =================
// blocks [0,256):   graph prep (LDS histogram+compact) + slots/cnt + h1 (3 nodes)
// blocks [256,512): Wcombo = Wc2 @ [We1a | We1b]  (+ bias_c row)
__global__ __launch_bounds__(256) void k_front(
    const float* __restrict__ x, const int* __restrict__ ei,
    const float* __restrict__ Wc1, const float* __restrict__ bc1,
    const float* __restrict__ Wc2, const float* __restrict__ bc2,
    const float* __restrict__ We1, const float* __restrict__ be1,
    int* __restrict__ cnt_g, int* __restrict__ slots,
    float* __restrict__ h1, float* __restrict__ Wcombo, float* __restrict__ bias_c)
{
    const int t = threadIdx.x;
    if (blockIdx.x < 256) {
        __shared__ int s_cnt[N_NODES];
        __shared__ int s_list[LC];
        __shared__ int s_nm;
        __shared__ int s_pos[3];
        __shared__ float s_agg[3][D_INF];
        const int b = blockIdx.x, v0 = b * 3;
        const int* src = ei;
        const int* dst = ei + N_EDGES;
        for (int v = t; v < N_NODES; v += 256) s_cnt[v] = 0;
        if (t == 0) s_nm = 0;
        if (t < 3) s_pos[t] = 0;
        if (t < 3 * D_INF) ((float*)s_agg)[t] = 0.f;
        __syncthreads();
        for (int e = t; e < N_EDGES; e += 256) {
            int d = dst[e];
            atomicAdd(&s_cnt[d], 1);
            unsigned li = (unsigned)(d - v0);
            if (li < 3u) {
                int s = src[e];
                int p = atomicAdd(&s_nm, 1);
                if (p < LC) s_list[p] = (s << 2) | (int)li;
            }
        }
        __syncthreads();
        const int nm = min(s_nm, LC);
        if (t < 3) cnt_g[v0 + t] = s_cnt[v0 + t];
        for (int m = t; m < nm; m += 256) {
            int pk = s_list[m];
            int s = pk >> 2, li = pk & 3;
            int p = atomicAdd(&s_pos[li], 1);
            if (p < CAP) slots[(v0 + li) * CAP + p] = s;
            float w = rsqrtf((float)(s_cnt[s] + 1)) * rsqrtf((float)(s_cnt[v0 + li] + 1));
            #pragma unroll
            for (int k = 0; k < D_INF; ++k)
                atomicAdd(&s_agg[li][k], w * x[s * D_INF + k]);
        }
        if (t < 3) {   // self-loops
            int v = v0 + t;
            float dv2 = 1.0f / (float)(s_cnt[v] + 1);
            #pragma unroll
            for (int k = 0; k < D_INF; ++k)
                atomicAdd(&s_agg[t][k], dv2 * x[v * D_INF + k]);
        }
        __syncthreads();
        #pragma unroll
        for (int r = 0; r < 3; ++r) {
            float acc = bc1[t];
            #pragma unroll
            for (int k = 0; k < D_INF; ++k)
                acc = fmaf(s_agg[r][k], Wc1[k * H + t], acc);
            h1[(v0 + r) * H + t] = (acc > 0.f) ? acc : expm1f(acc);
        }
    } else {
        __shared__ __align__(16) float s_a[32 * SA];    // Wc2 rows tile
        __shared__ __align__(16) float s_bT[16 * SA];   // We1x col panel (transposed)
        __shared__ float s_bc2[H];
        const int idx = blockIdx.x - 256;
        const int rg = idx >> 5, cp = idx & 31;         // 8 rg x 32 cp
        const int r0 = rg * 32, c0 = cp * 16;
        const int c = t & 15, ro = t >> 4;
        for (int i = t; i < 32 * 64; i += 256) {
            int r = i >> 6, q = i & 63;
            float4 v = *(const float4*)(Wc2 + (size_t)(r0 + r) * H + q * 4);
            *(float4*)&s_a[r * SA + q * 4] = v;
        }
        {
            int kk = t >> 4, cc = t & 15;
            int cg = c0 + cc;
            const float* Wsrc = (cg < H) ? (We1 + cg)
                                         : (We1 + (size_t)H * H + (cg - H));
            #pragma unroll
            for (int it = 0; it < 16; ++it) {
                int k = kk + it * 16;
                s_bT[cc * SA + k] = Wsrc[(size_t)k * H];
            }
        }
        s_bc2[t] = bc2[t];
        __syncthreads();
        float a0 = 0.f, a1 = 0.f;
        #pragma unroll 8
        for (int kg = 0; kg < 64; ++kg) {
            float4 w  = *(const float4*)&s_bT[c * SA + kg * 4];
            float4 v0 = *(const float4*)&s_a[(ro)      * SA + kg * 4];
            float4 v1 = *(const float4*)&s_a[(ro + 16) * SA + kg * 4];
            a0 = fmaf(v0.x, w.x, a0); a0 = fmaf(v0.y, w.y, a0);
            a0 = fmaf(v0.z, w.z, a0); a0 = fmaf(v0.w, w.w, a0);
            a1 = fmaf(v1.x, w.x, a1); a1 = fmaf(v1.y, w.y, a1);
            a1 = fmaf(v1.z, w.z, a1); a1 = fmaf(v1.w, w.w, a1);
        }
        Wcombo[(size_t)(r0 + ro)      * H2 + c0 + c] = a0;
        Wcombo[(size_t)(r0 + ro + 16) * H2 + c0 + c] = a1;
        if (rg == 0 && t < 16) {    // bias_c = bc2 @ We1x (+ be1 for j-half)
            int cg = c0 + t;
            float bias = (cg >= H) ? be1[cg - H] : 0.f;
            for (int k = 0; k < H; ++k)
                bias = fmaf(s_bc2[k], s_bT[t * SA + k], bias);
            bias_c[cg] = bias;
        }
    }
}

// ================= K2 k_agg: agg2 = (A h1), 1 node/block, (s,w) preloaded ========
__global__ __launch_bounds__(256) void k_agg(
    const float* __restrict__ h1, const int* __restrict__ cnt,
    const int* __restrict__ slots, float* __restrict__ agg2) {
    __shared__ int   s_s[CAP];
    __shared__ float s_w[CAP];
    const int v = blockIdx.x, t = threadIdx.x;
    const int c = cnt[v];
    const int cc = min(c, CAP);
    const float dv = rsqrtf((float)(c + 1));
    for (int i = t; i < cc; i += 256) {
        int s = slots[v * CAP + i];
        s_s[i] = s;
        s_w[i] = rsqrtf((float)(cnt[s] + 1)) * dv;
    }
    __syncthreads();
    float acc = dv * dv * h1[v * H + t];
    #pragma unroll 4
    for (int n = 0; n < cc; ++n)
        acc = fmaf(s_w[n], h1[s_s[n] * H + t], acc);
    agg2[v * H + t] = acc;
}

// ================= K3 k_ae2: [aib | ajcT] = agg2 @ Wcombo + bias_c =================
// grid 768 = 24 rg (32 rows) x 32 cp (16 of 512 cols)
__global__ __launch_bounds__(256) void k_ae2(
    const float* __restrict__ agg2, const float* __restrict__ Wcombo,
    const float* __restrict__ bias_c, float* __restrict__ aib,
    float* __restrict__ ajcT) {
    __shared__ __align__(16) float s_h[32 * SA];
    __shared__ __align__(16) float s_wT[16 * SA];
    const int t = threadIdx.x, b = blockIdx.x;
    const int rg = b >> 5, cp = b & 31;
    const int j0 = rg * 32, c0 = cp * 16;
    const int c = t & 15, ro = t >> 4;

    for (int i = t; i < 32 * 64; i += 256) {
        int r = i >> 6, q = i & 63;
        float4 v = *(const float4*)(agg2 + (size_t)(j0 + r) * H + q * 4);
        *(float4*)&s_h[r * SA + q * 4] = v;
    }
    {
        int kk = t >> 4, cc = t & 15;
        #pragma unroll
        for (int it = 0; it < 16; ++it) {
            int k = kk + it * 16;
            s_wT[cc * SA + k] = Wcombo[(size_t)k * H2 + c0 + cc];
        }
    }
    __syncthreads();

    float pa0 = 0.f, pa1 = 0.f;
    #pragma unroll 8
    for (int kg = 0; kg < 64; ++kg) {
        float4 w  = *(const float4*)&s_wT[c * SA + kg * 4];
        float4 v0 = *(const float4*)&s_h[(ro)      * SA + kg * 4];
        float4 v1 = *(const float4*)&s_h[(ro + 16) * SA + kg * 4];
        pa0 = fmaf(v0.x, w.x, pa0); pa0 = fmaf(v0.y, w.y, pa0);
        pa0 = fmaf(v0.z, w.z, pa0); pa0 = fmaf(v0.w, w.w, pa0);
        pa1 = fmaf(v1.x, w.x, pa1); pa1 = fmaf(v1.y, w.y, pa1);
        pa1 = fmaf(v1.z, w.z, pa1); pa1 = fmaf(v1.w, w.w, pa1);
    }
    int cg = c0 + c;
    float bb = bias_c[cg];
    if (cg < H) {
        aib[(size_t)(j0 + ro)      * H + cg] = pa0 + bb;
        aib[(size_t)(j0 + ro + 16) * H + cg] = pa1 + bb;
    } else {
        ajcT[(size_t)(cg - H) * N_NODES + j0 + ro]      = pa0 + bb;
        ajcT[(size_t)(cg - H) * N_NODES + j0 + ro + 16] = pa1 + bb;
    }
}

// ================= K4 k_pairA: partial logits over h-chunks =================
// grid 256 = 64 rg (12 rows) x 4 hp (64-h chunk); 512 thr: th half = 6 rows
// logits_p[hp][i][j] = sum_{h in chunk} relu(ai[i,h]+ajcT[h,j]) * w2[h]
__global__ __launch_bounds__(512) void k_pairA(
    const float* __restrict__ aib, const float* __restrict__ ajcT,
    const float* __restrict__ We2, float* __restrict__ logits_p) {
    __shared__ float s_ai[12 * H];
    __shared__ float s_w2[H];
    const int t = threadIdx.x, b = blockIdx.x;
    const int tc = t & 255, th = t >> 8;
    const int rg = b >> 2, hp = b & 3;
    const int i0 = rg * 12, h0 = hp * 64;

    for (int i = t; i < 12 * H; i += 512) {
        int r = i >> 8, col = i & 255;
        s_ai[r * H + col] = aib[(size_t)(i0 + r) * H + col];
    }
    if (t < H) s_w2[t] = We2[t];
    __syncthreads();

    const int r0 = th * 6;
    float acc[6][3];
    #pragma unroll
    for (int r = 0; r < 6; ++r)
        #pragma unroll
        for (int jj = 0; jj < 3; ++jj) acc[r][jj] = 0.f;

    #pragma unroll 4
    for (int hh = 0; hh < 64; ++hh) {
        int h = h0 + hh;
        float wv = s_w2[h];
        const float* col = ajcT + (size_t)h * N_NODES;
        float b0 = col[tc], b1 = col[tc + 256], b2 = col[tc + 512];
        #pragma unroll
        for (int r = 0; r < 6; ++r) {
            float av = s_ai[(r0 + r) * H + h];
            acc[r][0] = fmaf(fmaxf(av + b0, 0.f), wv, acc[r][0]);
            acc[r][1] = fmaf(fmaxf(av + b1, 0.f), wv, acc[r][1]);
            acc[r][2] = fmaf(fmaxf(av + b2, 0.f), wv, acc[r][2]);
        }
    }
    #pragma unroll
    for (int r = 0; r < 6; ++r) {
        float* row = logits_p + ((size_t)hp * N_NODES + i0 + r0 + r) * N_NODES;
        #pragma unroll
        for (int jj = 0; jj < 3; ++jj)
            row[tc + jj * 256] = acc[r][jj];
    }
}

// ================= K5 k_soft: sum partials + diag mask + row softmax ==============
__global__ __launch_bounds__(256) void k_soft(
    const float* __restrict__ logits_p, float* __restrict__ out) {
    __shared__ float red[256];
    const int i = blockIdx.x, t = threadIdx.x;
    float l[3];
    #pragma unroll
    for (int jj = 0; jj < 3; ++jj) {
        int j = t + jj * 256;
        float s = 0.f;
        #pragma unroll
        for (int hp = 0; hp < 4; ++hp)
            s += logits_p[((size_t)hp * N_NODES + i) * N_NODES + j];
        l[jj] = (j == i) ? -INFINITY : s;
    }
    red[t] = fmaxf(fmaxf(l[0], l[1]), l[2]);
    __syncthreads();
    for (int s = 128; s > 0; s >>= 1) {
        if (t < s) red[t] = fmaxf(red[t], red[t + s]);
        __syncthreads();
    }
    float mx = red[0];
    __syncthreads();
    float e0 = __expf(l[0] - mx), e1 = __expf(l[1] - mx), e2 = __expf(l[2] - mx);
    red[t] = e0 + e1 + e2;
    __syncthreads();
    for (int s = 128; s > 0; s >>= 1) {
        if (t < s) red[t] += red[t + s];
        __syncthreads();
    }
    float inv = 1.0f / red[0];
    out[(size_t)i * N_NODES + t]       = e0 * inv;
    out[(size_t)i * N_NODES + t + 256] = e1 * inv;
    out[(size_t)i * N_NODES + t + 512] = e2 * inv;
}

extern "C" void kernel_launch(void* const* d_in, const int* in_sizes, int n_in,
                              void* d_out, int out_size, void* d_ws, size_t ws_size,
                              hipStream_t stream) {
    const float* x   = (const float*)d_in[0];
    const int*   ei  = (const int*)d_in[1];
    const float* Wc1 = (const float*)d_in[2];
    const float* bc1 = (const float*)d_in[3];
    const float* Wc2 = (const float*)d_in[4];
    const float* bc2 = (const float*)d_in[5];
    const float* We1 = (const float*)d_in[6];
    const float* be1 = (const float*)d_in[7];
    const float* We2 = (const float*)d_in[8];
    // be2 (d_in[9]) unused: softmax shift-invariant (TEMPERATURE=1 likewise).
    float* out = (float*)d_out;

    char* ws = (char*)d_ws;
    int*   cnt      = (int*)(ws + 0);          // 3072
    int*   slots    = (int*)(ws + 4096);       // 393216
    float* h1       = (float*)(ws + 397312);   // 786432
    float* agg2     = (float*)(ws + 1183744);  // 786432
    float* aib      = (float*)(ws + 1970176);  // 786432
    float* ajcT     = (float*)(ws + 2756608);  // 786432
    float* Wcombo   = (float*)(ws + 3543040);  // 524288
    float* bias_c   = (float*)(ws + 4067328);  // 2048
    float* logits_p = (float*)(ws + 4069376);  // 9437184

    k_front<<<512, 256, 0, stream>>>(x, ei, Wc1, bc1, Wc2, bc2, We1, be1,
                                     cnt, slots, h1, Wcombo, bias_c);
    k_agg<<<N_NODES, 256, 0, stream>>>(h1, cnt, slots, agg2);
    k_ae2<<<768, 256, 0, stream>>>(agg2, Wcombo, bias_c, aib, ajcT);
    k_pairA<<<256, 512, 0, stream>>>(aib, ajcT, We2, logits_p);
    k_soft<<<N_NODES, 256, 0, stream>>>(logits_p, out);
}

// Round 11
// 54.678 us; speedup vs baseline: 4.1624x; 1.0480x over previous
//
#include <hip/hip_runtime.h>
#include <math.h>

#define N_NODES 768
#define N_EDGES 12288
#define D_INF 6
#define H 256
#define CAP 128
#define LC 256

// ============ K1 k_prep: LDS histogram + compact -> cnt/slots + h1 (3 nodes) ======
__global__ __launch_bounds__(256) void k_prep(
    const float* __restrict__ x, const int* __restrict__ ei,
    const float* __restrict__ Wc1, const float* __restrict__ bc1,
    int* __restrict__ cnt_g, int* __restrict__ slots, float* __restrict__ h1) {
    __shared__ int s_cnt[N_NODES];
    __shared__ int s_list[LC];
    __shared__ int s_nm, s_pos[3];
    __shared__ float s_agg[3][D_INF];
    const int t = threadIdx.x, b = blockIdx.x, v0 = b * 3;
    const int* src = ei;
    const int* dst = ei + N_EDGES;

    for (int v = t; v < N_NODES; v += 256) s_cnt[v] = 0;
    if (t == 0) s_nm = 0;
    if (t < 3) s_pos[t] = 0;
    if (t < 3 * D_INF) ((float*)s_agg)[t] = 0.f;
    __syncthreads();
    for (int e = t; e < N_EDGES; e += 256) {
        int d = dst[e];
        atomicAdd(&s_cnt[d], 1);
        unsigned li = (unsigned)(d - v0);
        if (li < 3u) {
            int p = atomicAdd(&s_nm, 1);
            if (p < LC) s_list[p] = (src[e] << 2) | (int)li;
        }
    }
    __syncthreads();
    const int nm = min(s_nm, LC);
    if (t < 3) cnt_g[v0 + t] = s_cnt[v0 + t];
    for (int m = t; m < nm; m += 256) {
        int pk = s_list[m];
        int s = pk >> 2, li = pk & 3;
        int p = atomicAdd(&s_pos[li], 1);
        if (p < CAP) slots[(v0 + li) * CAP + p] = s;
        float w = rsqrtf((float)(s_cnt[s] + 1)) * rsqrtf((float)(s_cnt[v0 + li] + 1));
        #pragma unroll
        for (int k = 0; k < D_INF; ++k)
            atomicAdd(&s_agg[li][k], w * x[s * D_INF + k]);
    }
    if (t < 3) {   // self-loops
        int v = v0 + t;
        float dv2 = 1.0f / (float)(s_cnt[v] + 1);
        #pragma unroll
        for (int k = 0; k < D_INF; ++k)
            atomicAdd(&s_agg[t][k], dv2 * x[v * D_INF + k]);
    }
    __syncthreads();
    #pragma unroll
    for (int r = 0; r < 3; ++r) {
        float acc = bc1[t];
        #pragma unroll
        for (int k = 0; k < D_INF; ++k)
            acc = fmaf(s_agg[r][k], Wc1[k * H + t], acc);
        h1[(v0 + r) * H + t] = (acc > 0.f) ? acc : expm1f(acc);
    }
}

// ============ K2 k_agg: agg2 = (A h1), 1 node/block, (s,w) preloaded ============
__global__ __launch_bounds__(256) void k_agg(
    const float* __restrict__ h1, const int* __restrict__ cnt,
    const int* __restrict__ slots, float* __restrict__ agg2) {
    __shared__ int   s_s[CAP];
    __shared__ float s_w[CAP];
    const int v = blockIdx.x, t = threadIdx.x;
    const int c = cnt[v];
    const int cc = min(c, CAP);
    const float dv = rsqrtf((float)(c + 1));
    for (int i = t; i < cc; i += 256) {
        int s = slots[v * CAP + i];
        s_s[i] = s;
        s_w[i] = rsqrtf((float)(cnt[s] + 1)) * dv;
    }
    __syncthreads();
    float acc = dv * dv * h1[v * H + t];
    #pragma unroll 4
    for (int n = 0; n < cc; ++n)
        acc = fmaf(s_w[n], h1[s_s[n] * H + t], acc);
    agg2[v * H + t] = acc;
}

// ============ K3 k_h2: h2 = agg2 @ Wc2 + bc2 ============
// 3 rows/block, 1024 thr = 16 waves k-split 16 each; A in registers (uniform
// global loads, L1 broadcast), W streamed global b128 -> NO LDS in inner loop.
__global__ __launch_bounds__(1024) void k_h2(
    const float* __restrict__ agg2, const float* __restrict__ Wc2,
    const float* __restrict__ bc2, float* __restrict__ h2) {
    __shared__ __align__(16) float s_part[16][3][H];   // 49.2 KB
    const int t = threadIdx.x, b = blockIdx.x;
    const int lane = t & 63, w = t >> 6;
    const int v0 = b * 3, k0 = w * 16;

    float a[3][16];
    #pragma unroll
    for (int r = 0; r < 3; ++r)
        #pragma unroll
        for (int q = 0; q < 4; ++q) {
            float4 v = *(const float4*)(agg2 + (size_t)(v0 + r) * H + k0 + q * 4);
            a[r][q * 4 + 0] = v.x; a[r][q * 4 + 1] = v.y;
            a[r][q * 4 + 2] = v.z; a[r][q * 4 + 3] = v.w;
        }
    float4 c0 = {0.f, 0.f, 0.f, 0.f}, c1 = c0, c2 = c0;
    #pragma unroll
    for (int kk = 0; kk < 16; ++kk) {
        float4 wv = *(const float4*)(Wc2 + (size_t)(k0 + kk) * H + (lane << 2));
        c0.x = fmaf(a[0][kk], wv.x, c0.x); c0.y = fmaf(a[0][kk], wv.y, c0.y);
        c0.z = fmaf(a[0][kk], wv.z, c0.z); c0.w = fmaf(a[0][kk], wv.w, c0.w);
        c1.x = fmaf(a[1][kk], wv.x, c1.x); c1.y = fmaf(a[1][kk], wv.y, c1.y);
        c1.z = fmaf(a[1][kk], wv.z, c1.z); c1.w = fmaf(a[1][kk], wv.w, c1.w);
        c2.x = fmaf(a[2][kk], wv.x, c2.x); c2.y = fmaf(a[2][kk], wv.y, c2.y);
        c2.z = fmaf(a[2][kk], wv.z, c2.z); c2.w = fmaf(a[2][kk], wv.w, c2.w);
    }
    *(float4*)&s_part[w][0][lane << 2] = c0;
    *(float4*)&s_part[w][1][lane << 2] = c1;
    *(float4*)&s_part[w][2][lane << 2] = c2;
    __syncthreads();
    if (t < 3 * H) {
        int r = t >> 8, c = t & 255;
        float v = bc2[c];
        #pragma unroll
        for (int ww = 0; ww < 16; ++ww) v += s_part[ww][r][c];
        h2[(size_t)(v0 + r) * H + c] = v;
    }
}

// ============ K4 k_ae: ai = h2@We1[:H]; ajT = (h2@We1[H:]+be1)^T ============
// same register-A / global-W structure; 512 output cols (2 b128 W per k).
__global__ __launch_bounds__(1024) void k_ae(
    const float* __restrict__ h2, const float* __restrict__ We1,
    const float* __restrict__ be1, float* __restrict__ aib,
    float* __restrict__ ajcT) {
    __shared__ __align__(16) float s_part[16][6][H];   // 98.3 KB
    const int t = threadIdx.x, b = blockIdx.x;
    const int lane = t & 63, w = t >> 6;
    const int v0 = b * 3, k0 = w * 16;

    float a[3][16];
    #pragma unroll
    for (int r = 0; r < 3; ++r)
        #pragma unroll
        for (int q = 0; q < 4; ++q) {
            float4 v = *(const float4*)(h2 + (size_t)(v0 + r) * H + k0 + q * 4);
            a[r][q * 4 + 0] = v.x; a[r][q * 4 + 1] = v.y;
            a[r][q * 4 + 2] = v.z; a[r][q * 4 + 3] = v.w;
        }
    float4 ca0 = {0.f, 0.f, 0.f, 0.f}, ca1 = ca0, ca2 = ca0;
    float4 cb0 = ca0, cb1 = ca0, cb2 = ca0;
    #pragma unroll
    for (int kk = 0; kk < 16; ++kk) {
        int k = k0 + kk;
        float4 wa = *(const float4*)(We1 + (size_t)k * H + (lane << 2));
        float4 wb = *(const float4*)(We1 + (size_t)(H + k) * H + (lane << 2));
        ca0.x = fmaf(a[0][kk], wa.x, ca0.x); ca0.y = fmaf(a[0][kk], wa.y, ca0.y);
        ca0.z = fmaf(a[0][kk], wa.z, ca0.z); ca0.w = fmaf(a[0][kk], wa.w, ca0.w);
        ca1.x = fmaf(a[1][kk], wa.x, ca1.x); ca1.y = fmaf(a[1][kk], wa.y, ca1.y);
        ca1.z = fmaf(a[1][kk], wa.z, ca1.z); ca1.w = fmaf(a[1][kk], wa.w, ca1.w);
        ca2.x = fmaf(a[2][kk], wa.x, ca2.x); ca2.y = fmaf(a[2][kk], wa.y, ca2.y);
        ca2.z = fmaf(a[2][kk], wa.z, ca2.z); ca2.w = fmaf(a[2][kk], wa.w, ca2.w);
        cb0.x = fmaf(a[0][kk], wb.x, cb0.x); cb0.y = fmaf(a[0][kk], wb.y, cb0.y);
        cb0.z = fmaf(a[0][kk], wb.z, cb0.z); cb0.w = fmaf(a[0][kk], wb.w, cb0.w);
        cb1.x = fmaf(a[1][kk], wb.x, cb1.x); cb1.y = fmaf(a[1][kk], wb.y, cb1.y);
        cb1.z = fmaf(a[1][kk], wb.z, cb1.z); cb1.w = fmaf(a[1][kk], wb.w, cb1.w);
        cb2.x = fmaf(a[2][kk], wb.x, cb2.x); cb2.y = fmaf(a[2][kk], wb.y, cb2.y);
        cb2.z = fmaf(a[2][kk], wb.z, cb2.z); cb2.w = fmaf(a[2][kk], wb.w, cb2.w);
    }
    *(float4*)&s_part[w][0][lane << 2] = ca0;
    *(float4*)&s_part[w][1][lane << 2] = ca1;
    *(float4*)&s_part[w][2][lane << 2] = ca2;
    *(float4*)&s_part[w][3][lane << 2] = cb0;
    *(float4*)&s_part[w][4][lane << 2] = cb1;
    *(float4*)&s_part[w][5][lane << 2] = cb2;
    __syncthreads();
    for (int idx = t; idx < 6 * H; idx += 1024) {
        int q = idx >> 8, c = idx & 255;
        float v = 0.f;
        #pragma unroll
        for (int ww = 0; ww < 16; ++ww) v += s_part[ww][q][c];
        if (q < 3) aib[(size_t)(v0 + q) * H + c] = v;
        else       ajcT[(size_t)c * N_NODES + v0 + (q - 3)] = v + be1[c];
    }
}

// ============ K5 k_pair2: logits + fused row softmax ============
// 512 thr = 8 waves x 32-h slices (each (i,h) broadcast read by exactly 1 wave);
// j as 3 x float4 chunks (b128 col loads); h-partials reduced in LDS.
__global__ __launch_bounds__(512) void k_pair2(
    const float* __restrict__ aib, const float* __restrict__ ajcT,
    const float* __restrict__ We2, float* __restrict__ out) {
    __shared__ float s_ai[3 * H];
    __shared__ float s_w2[H];
    __shared__ __align__(16) float s_p[8 * 3 * N_NODES];   // 73.7 KB
    __shared__ float s_lg[3 * N_NODES];
    __shared__ float red[3 * 256];
    const int t = threadIdx.x, b = blockIdx.x;
    const int lane = t & 63, w = t >> 6;
    const int i0 = b * 3, h0 = w * 32;

    for (int i = t; i < 3 * H; i += 512)
        s_ai[i] = aib[(size_t)(i0 + (i >> 8)) * H + (i & 255)];
    if (t < H) s_w2[t] = We2[t];
    __syncthreads();

    float4 acc[3][3];
    #pragma unroll
    for (int r = 0; r < 3; ++r)
        #pragma unroll
        for (int jj = 0; jj < 3; ++jj)
            acc[r][jj] = make_float4(0.f, 0.f, 0.f, 0.f);

    #pragma unroll 4
    for (int hh = 0; hh < 32; ++hh) {
        int h = h0 + hh;
        float wv = s_w2[h];
        float a0 = s_ai[h], a1 = s_ai[H + h], a2 = s_ai[2 * H + h];
        const float* col = ajcT + (size_t)h * N_NODES + (lane << 2);
        #pragma unroll
        for (int jj = 0; jj < 3; ++jj) {
            float4 bv = *(const float4*)(col + jj * 256);
            acc[0][jj].x = fmaf(fmaxf(a0 + bv.x, 0.f), wv, acc[0][jj].x);
            acc[0][jj].y = fmaf(fmaxf(a0 + bv.y, 0.f), wv, acc[0][jj].y);
            acc[0][jj].z = fmaf(fmaxf(a0 + bv.z, 0.f), wv, acc[0][jj].z);
            acc[0][jj].w = fmaf(fmaxf(a0 + bv.w, 0.f), wv, acc[0][jj].w);
            acc[1][jj].x = fmaf(fmaxf(a1 + bv.x, 0.f), wv, acc[1][jj].x);
            acc[1][jj].y = fmaf(fmaxf(a1 + bv.y, 0.f), wv, acc[1][jj].y);
            acc[1][jj].z = fmaf(fmaxf(a1 + bv.z, 0.f), wv, acc[1][jj].z);
            acc[1][jj].w = fmaf(fmaxf(a1 + bv.w, 0.f), wv, acc[1][jj].w);
            acc[2][jj].x = fmaf(fmaxf(a2 + bv.x, 0.f), wv, acc[2][jj].x);
            acc[2][jj].y = fmaf(fmaxf(a2 + bv.y, 0.f), wv, acc[2][jj].y);
            acc[2][jj].z = fmaf(fmaxf(a2 + bv.z, 0.f), wv, acc[2][jj].z);
            acc[2][jj].w = fmaf(fmaxf(a2 + bv.w, 0.f), wv, acc[2][jj].w);
        }
    }
    #pragma unroll
    for (int r = 0; r < 3; ++r)
        #pragma unroll
        for (int jj = 0; jj < 3; ++jj)
            *(float4*)&s_p[(w * 3 + r) * N_NODES + jj * 256 + (lane << 2)] = acc[r][jj];
    __syncthreads();

    // sum 8 h-partials + diag mask
    for (int idx = t; idx < 3 * N_NODES; idx += 512) {
        int r = idx / N_NODES, j = idx - r * N_NODES;
        float v = 0.f;
        #pragma unroll
        for (int ww = 0; ww < 8; ++ww) v += s_p[(ww * 3 + r) * N_NODES + j];
        s_lg[idx] = (j == i0 + r) ? -INFINITY : v;
    }
    __syncthreads();

    const int tc = t & 255, th = t >> 8;
    // row max (rows 0,2 on th0; row 1 on th1)
    if (th == 0) {
        red[tc] = fmaxf(fmaxf(s_lg[tc], s_lg[tc + 256]), s_lg[tc + 512]);
        red[512 + tc] = fmaxf(fmaxf(s_lg[1536 + tc], s_lg[1536 + tc + 256]),
                              s_lg[1536 + tc + 512]);
    } else {
        red[256 + tc] = fmaxf(fmaxf(s_lg[768 + tc], s_lg[768 + tc + 256]),
                              s_lg[768 + tc + 512]);
    }
    __syncthreads();
    for (int s = 128; s > 0; s >>= 1) {
        if (th == 0 && tc < s) {
            red[tc] = fmaxf(red[tc], red[tc + s]);
            red[512 + tc] = fmaxf(red[512 + tc], red[512 + tc + s]);
        } else if (th == 1 && tc < s) {
            red[256 + tc] = fmaxf(red[256 + tc], red[256 + tc + s]);
        }
        __syncthreads();
    }
    float mx0 = red[0], mx1 = red[256], mx2 = red[512];
    __syncthreads();
    // row sums of exp
    if (th == 0) {
        red[tc] = __expf(s_lg[tc] - mx0) + __expf(s_lg[tc + 256] - mx0)
                + __expf(s_lg[tc + 512] - mx0);
        red[512 + tc] = __expf(s_lg[1536 + tc] - mx2) + __expf(s_lg[1536 + tc + 256] - mx2)
                      + __expf(s_lg[1536 + tc + 512] - mx2);
    } else {
        red[256 + tc] = __expf(s_lg[768 + tc] - mx1) + __expf(s_lg[768 + tc + 256] - mx1)
                      + __expf(s_lg[768 + tc + 512] - mx1);
    }
    __syncthreads();
    for (int s = 128; s > 0; s >>= 1) {
        if (th == 0 && tc < s) {
            red[tc] += red[tc + s];
            red[512 + tc] += red[512 + tc + s];
        } else if (th == 1 && tc < s) {
            red[256 + tc] += red[256 + tc + s];
        }
        __syncthreads();
    }
    float iv0 = 1.0f / red[0], iv1 = 1.0f / red[256], iv2 = 1.0f / red[512];

    for (int idx = t; idx < 3 * N_NODES; idx += 512) {
        int r = idx / N_NODES, j = idx - r * N_NODES;
        float m = (r == 0) ? mx0 : (r == 1) ? mx1 : mx2;
        float iv = (r == 0) ? iv0 : (r == 1) ? iv1 : iv2;
        out[(size_t)(i0 + r) * N_NODES + j] = __expf(s_lg[idx] - m) * iv;
    }
}

extern "C" void kernel_launch(void* const* d_in, const int* in_sizes, int n_in,
                              void* d_out, int out_size, void* d_ws, size_t ws_size,
                              hipStream_t stream) {
    const float* x   = (const float*)d_in[0];
    const int*   ei  = (const int*)d_in[1];
    const float* Wc1 = (const float*)d_in[2];
    const float* bc1 = (const float*)d_in[3];
    const float* Wc2 = (const float*)d_in[4];
    const float* bc2 = (const float*)d_in[5];
    const float* We1 = (const float*)d_in[6];
    const float* be1 = (const float*)d_in[7];
    const float* We2 = (const float*)d_in[8];
    // be2 (d_in[9]) unused: softmax shift-invariant (TEMPERATURE=1 likewise).
    float* out = (float*)d_out;

    char* ws = (char*)d_ws;
    int*   cnt  = (int*)(ws + 0);            // 3072
    int*   slots= (int*)(ws + 4096);         // 393216
    float* h1   = (float*)(ws + 397312);     // 786432
    float* agg2 = (float*)(ws + 1183744);    // 786432
    float* h2   = (float*)(ws + 1970176);    // 786432
    float* aib  = (float*)(ws + 2756608);    // 786432
    float* ajcT = (float*)(ws + 3543040);    // 786432

    k_prep<<<N_NODES / 3, 256, 0, stream>>>(x, ei, Wc1, bc1, cnt, slots, h1);
    k_agg<<<N_NODES, 256, 0, stream>>>(h1, cnt, slots, agg2);
    k_h2<<<N_NODES / 3, 1024, 0, stream>>>(agg2, Wc2, bc2, h2);
    k_ae<<<N_NODES / 3, 1024, 0, stream>>>(h2, We1, be1, aib, ajcT);
    k_pair2<<<N_NODES / 3, 512, 0, stream>>>(aib, ajcT, We2, out);
}

// Round 12
// 51.741 us; speedup vs baseline: 4.3987x; 1.0568x over previous
//
#include <hip/hip_runtime.h>
#include <math.h>

#define N_NODES 768
#define N_EDGES 12288
#define D_INF 6
#define H 256
#define CAP 128
#define LC 256

// ============ K1 k_prep: LDS histogram + compact -> cnt/slots + h1 (3 nodes) ======
__global__ __launch_bounds__(256) void k_prep(
    const float* __restrict__ x, const int* __restrict__ ei,
    const float* __restrict__ Wc1, const float* __restrict__ bc1,
    int* __restrict__ cnt_g, int* __restrict__ slots, float* __restrict__ h1) {
    __shared__ int s_cnt[N_NODES];
    __shared__ int s_list[LC];
    __shared__ int s_nm, s_pos[3];
    __shared__ float s_agg[3][D_INF];
    const int t = threadIdx.x, b = blockIdx.x, v0 = b * 3;
    const int* src = ei;
    const int* dst = ei + N_EDGES;

    for (int v = t; v < N_NODES; v += 256) s_cnt[v] = 0;
    if (t == 0) s_nm = 0;
    if (t < 3) s_pos[t] = 0;
    if (t < 3 * D_INF) ((float*)s_agg)[t] = 0.f;
    __syncthreads();
    for (int e = t; e < N_EDGES; e += 256) {
        int d = dst[e];
        atomicAdd(&s_cnt[d], 1);
        unsigned li = (unsigned)(d - v0);
        if (li < 3u) {
            int p = atomicAdd(&s_nm, 1);
            if (p < LC) s_list[p] = (src[e] << 2) | (int)li;
        }
    }
    __syncthreads();
    const int nm = min(s_nm, LC);
    if (t < 3) cnt_g[v0 + t] = s_cnt[v0 + t];
    for (int m = t; m < nm; m += 256) {
        int pk = s_list[m];
        int s = pk >> 2, li = pk & 3;
        int p = atomicAdd(&s_pos[li], 1);
        if (p < CAP) slots[(v0 + li) * CAP + p] = s;
        float w = rsqrtf((float)(s_cnt[s] + 1)) * rsqrtf((float)(s_cnt[v0 + li] + 1));
        #pragma unroll
        for (int k = 0; k < D_INF; ++k)
            atomicAdd(&s_agg[li][k], w * x[s * D_INF + k]);
    }
    if (t < 3) {   // self-loops
        int v = v0 + t;
        float dv2 = 1.0f / (float)(s_cnt[v] + 1);
        #pragma unroll
        for (int k = 0; k < D_INF; ++k)
            atomicAdd(&s_agg[t][k], dv2 * x[v * D_INF + k]);
    }
    __syncthreads();
    #pragma unroll
    for (int r = 0; r < 3; ++r) {
        float acc = bc1[t];
        #pragma unroll
        for (int k = 0; k < D_INF; ++k)
            acc = fmaf(s_agg[r][k], Wc1[k * H + t], acc);
        h1[(v0 + r) * H + t] = (acc > 0.f) ? acc : expm1f(acc);
    }
}

// ============ K2 k_mid: agg(h1) -> h2 -> ai/ajcT, all row-local, 3 nodes/block ======
// 1024 thr. P1: gather (768 thr, preloaded (s,w)). P2: h2 = agg@Wc2+bc2
// (16-wave k-split, A from LDS broadcast, W streamed global b128).
// P3: [ai|ajT] = h2@We1 (+be1 on j-half), same structure, 6 outputs.
__global__ __launch_bounds__(1024) void k_mid(
    const float* __restrict__ h1, const int* __restrict__ cnt,
    const int* __restrict__ slots, const float* __restrict__ Wc2,
    const float* __restrict__ bc2, const float* __restrict__ We1,
    const float* __restrict__ be1, float* __restrict__ aib,
    float* __restrict__ ajcT) {
    __shared__ int   s_s[3][CAP];
    __shared__ float s_w[3][CAP];
    __shared__ int   s_cc[3];
    __shared__ float s_dv[3];
    __shared__ __align__(16) float s_agg[3][H];
    __shared__ __align__(16) float s_h2[3][H];
    __shared__ __align__(16) float s_part[16][6][H];   // 98.3 KB (P2 uses [..][0..2][..])
    const int t = threadIdx.x, b = blockIdx.x;
    const int q = t >> 8, tc = t & 255;
    const int lane = t & 63, w = t >> 6;
    const int v0 = b * 3, k0 = w * 16;

    // ---- P0: (s,w) preload, independent parallel loads ----
    if (t < 3) {
        int c = cnt[v0 + t];
        s_cc[t] = min(c, CAP);
        s_dv[t] = rsqrtf((float)(c + 1));
    }
    __syncthreads();
    if (q < 3) {
        int ccq = s_cc[q];
        for (int i = tc; i < ccq; i += 256) {
            int s = slots[(v0 + q) * CAP + i];
            s_s[q][i] = s;
            s_w[q][i] = rsqrtf((float)(cnt[s] + 1)) * s_dv[q];
        }
    }
    __syncthreads();

    // ---- P1: agg = (A h1) rows ----
    if (q < 3) {
        float dv = s_dv[q];
        float acc = dv * dv * h1[(size_t)(v0 + q) * H + tc];
        int ccq = s_cc[q];
        #pragma unroll 4
        for (int n = 0; n < ccq; ++n)
            acc = fmaf(s_w[q][n], h1[(size_t)s_s[q][n] * H + tc], acc);
        s_agg[q][tc] = acc;
    }
    __syncthreads();

    // ---- P2: h2 = agg @ Wc2 + bc2 ----
    {
        float a[3][16];
        #pragma unroll
        for (int r = 0; r < 3; ++r)
            #pragma unroll
            for (int qq = 0; qq < 4; ++qq) {
                float4 v = *(const float4*)&s_agg[r][k0 + qq * 4];
                a[r][qq * 4 + 0] = v.x; a[r][qq * 4 + 1] = v.y;
                a[r][qq * 4 + 2] = v.z; a[r][qq * 4 + 3] = v.w;
            }
        float4 c0 = {0.f, 0.f, 0.f, 0.f}, c1 = c0, c2 = c0;
        #pragma unroll
        for (int kk = 0; kk < 16; ++kk) {
            float4 wv = *(const float4*)(Wc2 + (size_t)(k0 + kk) * H + (lane << 2));
            c0.x = fmaf(a[0][kk], wv.x, c0.x); c0.y = fmaf(a[0][kk], wv.y, c0.y);
            c0.z = fmaf(a[0][kk], wv.z, c0.z); c0.w = fmaf(a[0][kk], wv.w, c0.w);
            c1.x = fmaf(a[1][kk], wv.x, c1.x); c1.y = fmaf(a[1][kk], wv.y, c1.y);
            c1.z = fmaf(a[1][kk], wv.z, c1.z); c1.w = fmaf(a[1][kk], wv.w, c1.w);
            c2.x = fmaf(a[2][kk], wv.x, c2.x); c2.y = fmaf(a[2][kk], wv.y, c2.y);
            c2.z = fmaf(a[2][kk], wv.z, c2.z); c2.w = fmaf(a[2][kk], wv.w, c2.w);
        }
        *(float4*)&s_part[w][0][lane << 2] = c0;
        *(float4*)&s_part[w][1][lane << 2] = c1;
        *(float4*)&s_part[w][2][lane << 2] = c2;
    }
    __syncthreads();
    if (t < 3 * H) {
        int r = t >> 8, c = t & 255;
        float v = bc2[c];
        #pragma unroll
        for (int ww = 0; ww < 16; ++ww) v += s_part[ww][r][c];
        s_h2[r][c] = v;
    }
    __syncthreads();

    // ---- P3: [ai | ajT] = h2 @ [We1a | We1b] (+be1 on j-half) ----
    {
        float a[3][16];
        #pragma unroll
        for (int r = 0; r < 3; ++r)
            #pragma unroll
            for (int qq = 0; qq < 4; ++qq) {
                float4 v = *(const float4*)&s_h2[r][k0 + qq * 4];
                a[r][qq * 4 + 0] = v.x; a[r][qq * 4 + 1] = v.y;
                a[r][qq * 4 + 2] = v.z; a[r][qq * 4 + 3] = v.w;
            }
        float4 ca0 = {0.f, 0.f, 0.f, 0.f}, ca1 = ca0, ca2 = ca0;
        float4 cb0 = ca0, cb1 = ca0, cb2 = ca0;
        #pragma unroll
        for (int kk = 0; kk < 16; ++kk) {
            int k = k0 + kk;
            float4 wa = *(const float4*)(We1 + (size_t)k * H + (lane << 2));
            float4 wb = *(const float4*)(We1 + (size_t)(H + k) * H + (lane << 2));
            ca0.x = fmaf(a[0][kk], wa.x, ca0.x); ca0.y = fmaf(a[0][kk], wa.y, ca0.y);
            ca0.z = fmaf(a[0][kk], wa.z, ca0.z); ca0.w = fmaf(a[0][kk], wa.w, ca0.w);
            ca1.x = fmaf(a[1][kk], wa.x, ca1.x); ca1.y = fmaf(a[1][kk], wa.y, ca1.y);
            ca1.z = fmaf(a[1][kk], wa.z, ca1.z); ca1.w = fmaf(a[1][kk], wa.w, ca1.w);
            ca2.x = fmaf(a[2][kk], wa.x, ca2.x); ca2.y = fmaf(a[2][kk], wa.y, ca2.y);
            ca2.z = fmaf(a[2][kk], wa.z, ca2.z); ca2.w = fmaf(a[2][kk], wa.w, ca2.w);
            cb0.x = fmaf(a[0][kk], wb.x, cb0.x); cb0.y = fmaf(a[0][kk], wb.y, cb0.y);
            cb0.z = fmaf(a[0][kk], wb.z, cb0.z); cb0.w = fmaf(a[0][kk], wb.w, cb0.w);
            cb1.x = fmaf(a[1][kk], wb.x, cb1.x); cb1.y = fmaf(a[1][kk], wb.y, cb1.y);
            cb1.z = fmaf(a[1][kk], wb.z, cb1.z); cb1.w = fmaf(a[1][kk], wb.w, cb1.w);
            cb2.x = fmaf(a[2][kk], wb.x, cb2.x); cb2.y = fmaf(a[2][kk], wb.y, cb2.y);
            cb2.z = fmaf(a[2][kk], wb.z, cb2.z); cb2.w = fmaf(a[2][kk], wb.w, cb2.w);
        }
        *(float4*)&s_part[w][0][lane << 2] = ca0;
        *(float4*)&s_part[w][1][lane << 2] = ca1;
        *(float4*)&s_part[w][2][lane << 2] = ca2;
        *(float4*)&s_part[w][3][lane << 2] = cb0;
        *(float4*)&s_part[w][4][lane << 2] = cb1;
        *(float4*)&s_part[w][5][lane << 2] = cb2;
    }
    __syncthreads();
    for (int idx = t; idx < 6 * H; idx += 1024) {
        int r6 = idx >> 8, c = idx & 255;
        float v = 0.f;
        #pragma unroll
        for (int ww = 0; ww < 16; ++ww) v += s_part[ww][r6][c];
        if (r6 < 3) aib[(size_t)(v0 + r6) * H + c] = v;
        else        ajcT[(size_t)c * N_NODES + v0 + (r6 - 3)] = v + be1[c];
    }
}

// ============ K3 k_pair2: logits + fused row softmax ============
// 512 thr = 8 waves x 32-h slices; j as 3 x float4 chunks; partials in LDS.
__global__ __launch_bounds__(512) void k_pair2(
    const float* __restrict__ aib, const float* __restrict__ ajcT,
    const float* __restrict__ We2, float* __restrict__ out) {
    __shared__ float s_ai[3 * H];
    __shared__ float s_w2[H];
    __shared__ __align__(16) float s_p[8 * 3 * N_NODES];   // 73.7 KB
    __shared__ float s_lg[3 * N_NODES];
    __shared__ float red[3 * 256];
    const int t = threadIdx.x, b = blockIdx.x;
    const int lane = t & 63, w = t >> 6;
    const int i0 = b * 3, h0 = w * 32;

    for (int i = t; i < 3 * H; i += 512)
        s_ai[i] = aib[(size_t)(i0 + (i >> 8)) * H + (i & 255)];
    if (t < H) s_w2[t] = We2[t];
    __syncthreads();

    float4 acc[3][3];
    #pragma unroll
    for (int r = 0; r < 3; ++r)
        #pragma unroll
        for (int jj = 0; jj < 3; ++jj)
            acc[r][jj] = make_float4(0.f, 0.f, 0.f, 0.f);

    #pragma unroll 4
    for (int hh = 0; hh < 32; ++hh) {
        int h = h0 + hh;
        float wv = s_w2[h];
        float a0 = s_ai[h], a1 = s_ai[H + h], a2 = s_ai[2 * H + h];
        const float* col = ajcT + (size_t)h * N_NODES + (lane << 2);
        #pragma unroll
        for (int jj = 0; jj < 3; ++jj) {
            float4 bv = *(const float4*)(col + jj * 256);
            acc[0][jj].x = fmaf(fmaxf(a0 + bv.x, 0.f), wv, acc[0][jj].x);
            acc[0][jj].y = fmaf(fmaxf(a0 + bv.y, 0.f), wv, acc[0][jj].y);
            acc[0][jj].z = fmaf(fmaxf(a0 + bv.z, 0.f), wv, acc[0][jj].z);
            acc[0][jj].w = fmaf(fmaxf(a0 + bv.w, 0.f), wv, acc[0][jj].w);
            acc[1][jj].x = fmaf(fmaxf(a1 + bv.x, 0.f), wv, acc[1][jj].x);
            acc[1][jj].y = fmaf(fmaxf(a1 + bv.y, 0.f), wv, acc[1][jj].y);
            acc[1][jj].z = fmaf(fmaxf(a1 + bv.z, 0.f), wv, acc[1][jj].z);
            acc[1][jj].w = fmaf(fmaxf(a1 + bv.w, 0.f), wv, acc[1][jj].w);
            acc[2][jj].x = fmaf(fmaxf(a2 + bv.x, 0.f), wv, acc[2][jj].x);
            acc[2][jj].y = fmaf(fmaxf(a2 + bv.y, 0.f), wv, acc[2][jj].y);
            acc[2][jj].z = fmaf(fmaxf(a2 + bv.z, 0.f), wv, acc[2][jj].z);
            acc[2][jj].w = fmaf(fmaxf(a2 + bv.w, 0.f), wv, acc[2][jj].w);
        }
    }
    #pragma unroll
    for (int r = 0; r < 3; ++r)
        #pragma unroll
        for (int jj = 0; jj < 3; ++jj)
            *(float4*)&s_p[(w * 3 + r) * N_NODES + jj * 256 + (lane << 2)] = acc[r][jj];
    __syncthreads();

    for (int idx = t; idx < 3 * N_NODES; idx += 512) {
        int r = idx / N_NODES, j = idx - r * N_NODES;
        float v = 0.f;
        #pragma unroll
        for (int ww = 0; ww < 8; ++ww) v += s_p[(ww * 3 + r) * N_NODES + j];
        s_lg[idx] = (j == i0 + r) ? -INFINITY : v;
    }
    __syncthreads();

    const int tc = t & 255, th = t >> 8;
    if (th == 0) {
        red[tc] = fmaxf(fmaxf(s_lg[tc], s_lg[tc + 256]), s_lg[tc + 512]);
        red[512 + tc] = fmaxf(fmaxf(s_lg[1536 + tc], s_lg[1536 + tc + 256]),
                              s_lg[1536 + tc + 512]);
    } else {
        red[256 + tc] = fmaxf(fmaxf(s_lg[768 + tc], s_lg[768 + tc + 256]),
                              s_lg[768 + tc + 512]);
    }
    __syncthreads();
    for (int s = 128; s > 0; s >>= 1) {
        if (th == 0 && tc < s) {
            red[tc] = fmaxf(red[tc], red[tc + s]);
            red[512 + tc] = fmaxf(red[512 + tc], red[512 + tc + s]);
        } else if (th == 1 && tc < s) {
            red[256 + tc] = fmaxf(red[256 + tc], red[256 + tc + s]);
        }
        __syncthreads();
    }
    float mx0 = red[0], mx1 = red[256], mx2 = red[512];
    __syncthreads();
    if (th == 0) {
        red[tc] = __expf(s_lg[tc] - mx0) + __expf(s_lg[tc + 256] - mx0)
                + __expf(s_lg[tc + 512] - mx0);
        red[512 + tc] = __expf(s_lg[1536 + tc] - mx2) + __expf(s_lg[1536 + tc + 256] - mx2)
                      + __expf(s_lg[1536 + tc + 512] - mx2);
    } else {
        red[256 + tc] = __expf(s_lg[768 + tc] - mx1) + __expf(s_lg[768 + tc + 256] - mx1)
                      + __expf(s_lg[768 + tc + 512] - mx1);
    }
    __syncthreads();
    for (int s = 128; s > 0; s >>= 1) {
        if (th == 0 && tc < s) {
            red[tc] += red[tc + s];
            red[512 + tc] += red[512 + tc + s];
        } else if (th == 1 && tc < s) {
            red[256 + tc] += red[256 + tc + s];
        }
        __syncthreads();
    }
    float iv0 = 1.0f / red[0], iv1 = 1.0f / red[256], iv2 = 1.0f / red[512];

    for (int idx = t; idx < 3 * N_NODES; idx += 512) {
        int r = idx / N_NODES, j = idx - r * N_NODES;
        float m = (r == 0) ? mx0 : (r == 1) ? mx1 : mx2;
        float iv = (r == 0) ? iv0 : (r == 1) ? iv1 : iv2;
        out[(size_t)(i0 + r) * N_NODES + j] = __expf(s_lg[idx] - m) * iv;
    }
}

extern "C" void kernel_launch(void* const* d_in, const int* in_sizes, int n_in,
                              void* d_out, int out_size, void* d_ws, size_t ws_size,
                              hipStream_t stream) {
    const float* x   = (const float*)d_in[0];
    const int*   ei  = (const int*)d_in[1];
    const float* Wc1 = (const float*)d_in[2];
    const float* bc1 = (const float*)d_in[3];
    const float* Wc2 = (const float*)d_in[4];
    const float* bc2 = (const float*)d_in[5];
    const float* We1 = (const float*)d_in[6];
    const float* be1 = (const float*)d_in[7];
    const float* We2 = (const float*)d_in[8];
    // be2 (d_in[9]) unused: softmax shift-invariant (TEMPERATURE=1 likewise).
    float* out = (float*)d_out;

    char* ws = (char*)d_ws;
    int*   cnt  = (int*)(ws + 0);            // 3072
    int*   slots= (int*)(ws + 4096);         // 393216
    float* h1   = (float*)(ws + 397312);     // 786432
    float* aib  = (float*)(ws + 1183744);    // 786432
    float* ajcT = (float*)(ws + 1970176);    // 786432

    k_prep<<<N_NODES / 3, 256, 0, stream>>>(x, ei, Wc1, bc1, cnt, slots, h1);
    k_mid<<<N_NODES / 3, 1024, 0, stream>>>(h1, cnt, slots, Wc2, bc2, We1, be1,
                                            aib, ajcT);
    k_pair2<<<N_NODES / 3, 512, 0, stream>>>(aib, ajcT, We2, out);
}